// Round 1
// baseline (726.826 us; speedup 1.0000x reference)
//
#include <hip/hip_runtime.h>
#include <hip/hip_bf16.h>
#include <stdint.h>

namespace {

constexpr int kT   = 2048;
constexpr int kHid = 2048;
constexpr int kH   = 16;
constexpr int kHK  = 8;
constexpr int kD   = 128;
constexpr int kFF  = 6144;

using bf16x8 = __attribute__((ext_vector_type(8))) short;
using f32x4  = __attribute__((ext_vector_type(4))) float;

__device__ __forceinline__ float bf2f(unsigned short u) {
    return __uint_as_float(((unsigned)u) << 16);
}
__device__ __forceinline__ unsigned short f2bf(float f) {
    unsigned u = __float_as_uint(f);
    return (unsigned short)((u + 0x7fffu + ((u >> 16) & 1u)) >> 16);
}
__device__ __forceinline__ void gload_lds16(const void* g, void* l) {
    __builtin_amdgcn_global_load_lds(
        (__attribute__((address_space(1))) void*)g,
        (__attribute__((address_space(3))) void*)l, 16, 0, 0);
}

// fp32 -> bf16 grid-stride convert (vectorized x4)
__global__ __launch_bounds__(256)
void cvt_f32_bf16(const float* __restrict__ src, unsigned short* __restrict__ dst, int n4) {
    int i = blockIdx.x * 256 + threadIdx.x;
    if (i < n4) {
        float4 v = ((const float4*)src)[i];
        ushort4 o;
        o.x = f2bf(v.x); o.y = f2bf(v.y); o.z = f2bf(v.z); o.w = f2bf(v.w);
        ((ushort4*)dst)[i] = o;
    }
}

// RMSNorm over HID=2048, fp32 in -> bf16 out. 1 block per row.
__global__ __launch_bounds__(256)
void rmsnorm_k(const float* __restrict__ x, const float* __restrict__ w,
               unsigned short* __restrict__ out) {
    const int row = blockIdx.x;
    const int tid = threadIdx.x;
    const float4* xr = (const float4*)(x + (size_t)row * kHid);
    float4 v0 = xr[tid];
    float4 v1 = xr[tid + 256];
    float ss = v0.x*v0.x + v0.y*v0.y + v0.z*v0.z + v0.w*v0.w
             + v1.x*v1.x + v1.y*v1.y + v1.z*v1.z + v1.w*v1.w;
#pragma unroll
    for (int m = 1; m < 64; m <<= 1) ss += __shfl_xor(ss, m);
    __shared__ float red[4];
    if ((tid & 63) == 0) red[tid >> 6] = ss;
    __syncthreads();
    float tot = red[0] + red[1] + red[2] + red[3];
    float rs = rsqrtf(tot * (1.0f / kHid) + 1e-6f);
    const float4* wv = (const float4*)w;
    float4 w0 = wv[tid], w1 = wv[tid + 256];
    ushort4 o0, o1;
    o0.x = f2bf(v0.x * rs * w0.x); o0.y = f2bf(v0.y * rs * w0.y);
    o0.z = f2bf(v0.z * rs * w0.z); o0.w = f2bf(v0.w * rs * w0.w);
    o1.x = f2bf(v1.x * rs * w1.x); o1.y = f2bf(v1.y * rs * w1.y);
    o1.z = f2bf(v1.z * rs * w1.z); o1.w = f2bf(v1.w * rs * w1.w);
    ushort4* orow = (ushort4*)(out + (size_t)row * kHid);
    orow[tid] = o0;
    orow[tid + 256] = o1;
}

// GEMM: C(M,N) = A(M,K)bf16 * B(N,K)bf16^T. 128x128 tile, BK=64, 4 waves.
// EPI: 0 = fp32 store, 1 = bf16 store, 2 = fp32 store + Res add,
//      3 = bf16 store of silu(G)*acc
template <int EPI>
__global__ __launch_bounds__(256)
void gemm_bt(const unsigned short* __restrict__ A,
             const unsigned short* __restrict__ B,
             void* __restrict__ C,
             const float* __restrict__ Res,
             const unsigned short* __restrict__ G,
             int M, int N, int K) {
    __shared__ unsigned short As[128 * 64];
    __shared__ unsigned short Bs[128 * 64];

    const int tid  = threadIdx.x;
    const int lane = tid & 63;
    const int l15  = lane & 15;
    const int g4   = lane >> 4;
    const int wid  = tid >> 6;
    const int wr   = wid >> 1;
    const int wc   = wid & 1;
    const int bm   = blockIdx.y * 128;
    const int bn   = blockIdx.x * 128;

    f32x4 acc[4][4] = {};

    for (int k0 = 0; k0 < K; k0 += 64) {
        // stage 16KB A-tile + 16KB B-tile. LDS dest linear, global source
        // pre-swizzled (XOR slot ^ (row&7)) so swizzled reads are conflict-free.
#pragma unroll
        for (int i = 0; i < 4; ++i) {
            int ch  = tid + i * 256;
            int row = ch >> 3;
            int c16 = ch & 7;
            int col = ((c16 ^ (row & 7)) << 3) + k0;
            gload_lds16(A + (size_t)(bm + row) * K + col, (char*)As + ch * 16);
            gload_lds16(B + (size_t)(bn + row) * K + col, (char*)Bs + ch * 16);
        }
        __syncthreads();
#pragma unroll
        for (int ks = 0; ks < 2; ++ks) {
            bf16x8 af[4], bfr[4];
#pragma unroll
            for (int m = 0; m < 4; ++m) {
                int ra = wr * 64 + m * 16 + l15;
                int aa = (ra * 128 + ks * 64 + g4 * 16) ^ ((ra & 7) << 4);
                af[m] = *(const bf16x8*)((const char*)As + aa);
                int rb = wc * 64 + m * 16 + l15;
                int ab = (rb * 128 + ks * 64 + g4 * 16) ^ ((rb & 7) << 4);
                bfr[m] = *(const bf16x8*)((const char*)Bs + ab);
            }
#pragma unroll
            for (int m = 0; m < 4; ++m)
#pragma unroll
                for (int n = 0; n < 4; ++n)
                    acc[m][n] = __builtin_amdgcn_mfma_f32_16x16x32_bf16(
                        af[m], bfr[n], acc[m][n], 0, 0, 0);
        }
        __syncthreads();
    }

#pragma unroll
    for (int m = 0; m < 4; ++m) {
#pragma unroll
        for (int n = 0; n < 4; ++n) {
            int row = bm + wr * 64 + m * 16 + g4 * 4;
            int col = bn + wc * 64 + n * 16 + l15;
#pragma unroll
            for (int r = 0; r < 4; ++r) {
                size_t idx = (size_t)(row + r) * N + col;
                float v = acc[m][n][r];
                if (EPI == 0) {
                    ((float*)C)[idx] = v;
                } else if (EPI == 1) {
                    ((unsigned short*)C)[idx] = f2bf(v);
                } else if (EPI == 2) {
                    ((float*)C)[idx] = v + Res[idx];
                } else {
                    float g = bf2f(G[idx]);
                    ((unsigned short*)C)[idx] = f2bf(g / (1.0f + __expf(-g)) * v);
                }
            }
        }
    }
}

// Fused per-head RMSNorm (D=128) + RoPE for q and k.
// qkv fp32 (T x 4096): cols [0,2048) q heads, [2048,3072) k heads.
// grid (T, 6), 4 waves/block, wave = one (t, head) row.
__global__ __launch_bounds__(256)
void qknorm_rope(const float* __restrict__ qkv, const int* __restrict__ positions,
                 const float* __restrict__ qnw, const float* __restrict__ knw,
                 unsigned short* __restrict__ Qo, unsigned short* __restrict__ Ko) {
    const int t    = blockIdx.x;
    const int j    = blockIdx.y * 4 + (threadIdx.x >> 6);  // 0..23
    const int lane = threadIdx.x & 63;
    const float* src = qkv + (size_t)t * 4096 + j * 128;
    float x1 = src[lane];
    float x2 = src[lane + 64];
    float ss = x1 * x1 + x2 * x2;
#pragma unroll
    for (int m = 1; m < 64; m <<= 1) ss += __shfl_xor(ss, m);
    float rs = rsqrtf(ss * (1.0f / 128.0f) + 1e-6f);
    const float* w = (j < 16) ? qnw : knw;
    float n1 = x1 * rs * w[lane];
    float n2 = x2 * rs * w[lane + 64];
    float inv = powf(1.0e6f, -(float)lane * (1.0f / 64.0f));
    float fr = (float)positions[t] * inv;
    float sn, cs;
    sincosf(fr, &sn, &cs);
    float o1 = n1 * cs - n2 * sn;
    float o2 = n2 * cs + n1 * sn;
    if (j < 16) {
        unsigned short* d = Qo + (size_t)t * (kH * kD) + j * kD;
        d[lane] = f2bf(o1);
        d[lane + 64] = f2bf(o2);
    } else {
        unsigned short* d = Ko + (size_t)t * (kHK * kD) + (j - 16) * kD;
        d[lane] = f2bf(o1);
        d[lane + 64] = f2bf(o2);
    }
}

// V transpose: qkv fp32 v-part (T x [3072+1024]) -> Vt bf16 (1024 x T)
__global__ __launch_bounds__(256)
void vtrans(const float* __restrict__ qkv, unsigned short* __restrict__ Vt) {
    __shared__ float tile[32][33];
    const int t0 = blockIdx.x * 32;
    const int d0 = blockIdx.y * 32;
    const int tc = threadIdx.x & 31;
    const int tr = threadIdx.x >> 5;  // 0..7
#pragma unroll
    for (int i = 0; i < 4; ++i) {
        int trow = tr + i * 8;
        tile[trow][tc] = qkv[(size_t)(t0 + trow) * 4096 + 3072 + d0 + tc];
    }
    __syncthreads();
#pragma unroll
    for (int i = 0; i < 4; ++i) {
        int drow = tr + i * 8;
        Vt[(size_t)(d0 + drow) * kT + t0 + tc] = f2bf(tile[tc][drow]);
    }
}

// Causal flash attention, bf16 MFMA 16x16x32.
// grid (T/64, H), 4 waves; wave owns 16 q rows, iterates kv chunks of 32.
__global__ __launch_bounds__(256)
void attn_fwd(const unsigned short* __restrict__ Q,   // T x (H*D)
              const unsigned short* __restrict__ Kc,  // T x (HK*D)
              const unsigned short* __restrict__ Vt,  // (HK*D) x T
              unsigned short* __restrict__ O) {       // T x (H*D)
    __shared__ unsigned short P_lds[4][16 * 32];

    const int lane = threadIdx.x & 63;
    const int l15  = lane & 15;
    const int g4   = lane >> 4;
    const int wid  = threadIdx.x >> 6;
    const int h    = blockIdx.y;
    const int hk   = h >> 1;
    const int q0   = blockIdx.x * 64 + wid * 16;

    bf16x8 qf[4];
#pragma unroll
    for (int ks = 0; ks < 4; ++ks)
        qf[ks] = *(const bf16x8*)(Q + (size_t)(q0 + l15) * (kH * kD) + h * kD + ks * 32 + g4 * 8);

    f32x4 oacc[8] = {};
    float mrow[4] = {-3e38f, -3e38f, -3e38f, -3e38f};
    float lrow[4] = {0.f, 0.f, 0.f, 0.f};
    const float scale = 0.08838834764831845f;  // 1/sqrt(128)

    const int nch = ((q0 + 15) >> 5) + 1;
    for (int c = 0; c < nch; ++c) {
        const int kv0 = c * 32;
        f32x4 s[2] = {};
#pragma unroll
        for (int half = 0; half < 2; ++half) {
#pragma unroll
            for (int ks = 0; ks < 4; ++ks) {
                bf16x8 kf = *(const bf16x8*)(Kc + (size_t)(kv0 + half * 16 + l15) * (kHK * kD)
                                             + hk * kD + ks * 32 + g4 * 8);
                s[half] = __builtin_amdgcn_mfma_f32_16x16x32_bf16(qf[ks], kf, s[half], 0, 0, 0);
            }
        }
        float pv[2][4];
#pragma unroll
        for (int half = 0; half < 2; ++half)
#pragma unroll
            for (int r = 0; r < 4; ++r) {
                float v = s[half][r] * scale;
                int qi = q0 + g4 * 4 + r;
                int ki = kv0 + half * 16 + l15;
                pv[half][r] = (ki > qi) ? -3e38f : v;
            }
        // online softmax: row r is held by the 16 lanes sharing g4
#pragma unroll
        for (int r = 0; r < 4; ++r) {
            float rm = fmaxf(pv[0][r], pv[1][r]);
#pragma unroll
            for (int msk = 1; msk < 16; msk <<= 1)
                rm = fmaxf(rm, __shfl_xor(rm, msk));
            float mnew = fmaxf(mrow[r], rm);
            float corr = __expf(mrow[r] - mnew);
            mrow[r] = mnew;
            lrow[r] *= corr;
#pragma unroll
            for (int c2 = 0; c2 < 8; ++c2)
                oacc[c2][r] *= corr;
        }
        float psum[4] = {0.f, 0.f, 0.f, 0.f};
#pragma unroll
        for (int half = 0; half < 2; ++half)
#pragma unroll
            for (int r = 0; r < 4; ++r) {
                float p = __expf(pv[half][r] - mrow[r]);
                psum[r] += p;
                P_lds[wid][(g4 * 4 + r) * 32 + half * 16 + l15] = f2bf(p);
            }
#pragma unroll
        for (int r = 0; r < 4; ++r) {
#pragma unroll
            for (int msk = 1; msk < 16; msk <<= 1)
                psum[r] += __shfl_xor(psum[r], msk);
            lrow[r] += psum[r];
        }
        asm volatile("s_waitcnt lgkmcnt(0)" ::: "memory");
        bf16x8 pa = *(const bf16x8*)(&P_lds[wid][l15 * 32 + g4 * 8]);
#pragma unroll
        for (int c2 = 0; c2 < 8; ++c2) {
            bf16x8 vf = *(const bf16x8*)(Vt + (size_t)(hk * kD + c2 * 16 + l15) * kT + kv0 + g4 * 8);
            oacc[c2] = __builtin_amdgcn_mfma_f32_16x16x32_bf16(pa, vf, oacc[c2], 0, 0, 0);
        }
        asm volatile("" ::: "memory");
    }
#pragma unroll
    for (int c2 = 0; c2 < 8; ++c2)
#pragma unroll
        for (int r = 0; r < 4; ++r) {
            float v = oacc[c2][r] / lrow[r];
            O[(size_t)(q0 + g4 * 4 + r) * (kH * kD) + h * kD + c2 * 16 + l15] = f2bf(v);
        }
}

}  // namespace

extern "C" void kernel_launch(void* const* d_in, const int* in_sizes, int n_in,
                              void* d_out, int out_size, void* d_ws, size_t ws_size,
                              hipStream_t stream) {
    (void)in_sizes; (void)n_in; (void)out_size; (void)ws_size;

    const int*   positions = (const int*)  d_in[0];
    const float* hidden    = (const float*)d_in[1];
    const float* wq  = (const float*)d_in[2];
    const float* wk  = (const float*)d_in[3];
    const float* wv  = (const float*)d_in[4];
    const float* wo  = (const float*)d_in[5];
    const float* qnw = (const float*)d_in[6];
    const float* knw = (const float*)d_in[7];
    const float* ln1 = (const float*)d_in[8];
    const float* ln2 = (const float*)d_in[9];
    const float* wg  = (const float*)d_in[10];
    const float* wu  = (const float*)d_in[11];
    const float* wd  = (const float*)d_in[12];

    char* ws = (char*)d_ws;
    // persistent region (136 MiB)
    unsigned short* WQKV = (unsigned short*)(ws + 0);          // 4096x2048 bf16
    unsigned short* WO   = (unsigned short*)(ws + 16777216);   // 2048x2048
    unsigned short* WG   = (unsigned short*)(ws + 25165824);   // 6144x2048
    unsigned short* WU   = (unsigned short*)(ws + 50331648);   // 6144x2048
    unsigned short* WD   = (unsigned short*)(ws + 75497472);   // 2048x6144
    unsigned short* XN1  = (unsigned short*)(ws + 100663296);  // T x 2048
    unsigned short* OATT = (unsigned short*)(ws + 109051904);  // T x 2048
    float*          H1   = (float*)(ws + 117440512);           // T x 2048 fp32
    unsigned short* XN2  = (unsigned short*)(ws + 134217728);  // T x 2048
    // region B (48 MiB, aliased): attention temporaries then MLP temporaries
    float*          QKVF = (float*)(ws + 142606336);           // T x 4096 fp32
    unsigned short* QB   = (unsigned short*)(ws + 176160768);  // T x 2048
    unsigned short* KB   = (unsigned short*)(ws + 184549376);  // T x 1024
    unsigned short* VT   = (unsigned short*)(ws + 188743680);  // 1024 x T
    unsigned short* GATE = (unsigned short*)(ws + 142606336);  // T x 6144 (alias)
    unsigned short* ACT  = (unsigned short*)(ws + 167772160);  // T x 6144 (alias)

    auto cvt = [&](const float* s, unsigned short* dst, size_t n) {
        int n4 = (int)(n / 4);
        cvt_f32_bf16<<<dim3((n4 + 255) / 256), dim3(256), 0, stream>>>(s, dst, n4);
    };

    // 1. weight conversion (fp32 -> bf16), wq/wk/wv packed as rows of WQKV
    cvt(wq, WQKV,                 (size_t)kH  * kD * kHid);
    cvt(wk, WQKV + 2048 * kHid,   (size_t)kHK * kD * kHid);
    cvt(wv, WQKV + 3072 * kHid,   (size_t)kHK * kD * kHid);
    cvt(wo, WO,                   (size_t)kHid * kH * kD);
    cvt(wg, WG,                   (size_t)kFF * kHid);
    cvt(wu, WU,                   (size_t)kFF * kHid);
    cvt(wd, WD,                   (size_t)kHid * kFF);

    // 2. RMSNorm1
    rmsnorm_k<<<dim3(kT), dim3(256), 0, stream>>>(hidden, ln1, XN1);

    // 3. fused QKV GEMM: (T x 2048) x (4096 x 2048)^T -> fp32
    gemm_bt<0><<<dim3(4096 / 128, kT / 128), dim3(256), 0, stream>>>(
        XN1, WQKV, QKVF, nullptr, nullptr, kT, 4096, kHid);

    // 4. per-head RMSNorm + RoPE for q,k -> bf16
    qknorm_rope<<<dim3(kT, 6), dim3(256), 0, stream>>>(QKVF, positions, qnw, knw, QB, KB);

    // 5. V transpose -> Vt bf16 (HK*D x T)
    vtrans<<<dim3(kT / 32, 1024 / 32), dim3(256), 0, stream>>>(QKVF, VT);

    // 6. causal flash attention
    attn_fwd<<<dim3(kT / 64, kH), dim3(256), 0, stream>>>(QB, KB, VT, OATT);

    // 7. O-proj GEMM + residual(hidden) -> H1 fp32
    gemm_bt<2><<<dim3(kHid / 128, kT / 128), dim3(256), 0, stream>>>(
        OATT, WO, H1, hidden, nullptr, kT, kHid, kHid);

    // 8. RMSNorm2
    rmsnorm_k<<<dim3(kT), dim3(256), 0, stream>>>(H1, ln2, XN2);

    // 9. gate GEMM -> bf16
    gemm_bt<1><<<dim3(kFF / 128, kT / 128), dim3(256), 0, stream>>>(
        XN2, WG, GATE, nullptr, nullptr, kT, kFF, kHid);

    // 10. up GEMM with fused silu(gate)*up epilogue -> bf16
    gemm_bt<3><<<dim3(kFF / 128, kT / 128), dim3(256), 0, stream>>>(
        XN2, WU, ACT, nullptr, GATE, kT, kFF, kHid);

    // 11. down GEMM + residual(H1) -> d_out fp32
    gemm_bt<2><<<dim3(kHid / 128, kT / 128), dim3(256), 0, stream>>>(
        ACT, WD, (float*)d_out, H1, nullptr, kT, kHid, kFF);
}

// Round 2
// 593.033 us; speedup vs baseline: 1.2256x; 1.2256x over previous
//
#include <hip/hip_runtime.h>
#include <hip/hip_bf16.h>
#include <stdint.h>

namespace {

constexpr int kT   = 2048;
constexpr int kHid = 2048;
constexpr int kH   = 16;
constexpr int kHK  = 8;
constexpr int kD   = 128;
constexpr int kFF  = 6144;

using bf16x8 = __attribute__((ext_vector_type(8))) short;
using f32x4  = __attribute__((ext_vector_type(4))) float;

__device__ __forceinline__ float bf2f(unsigned short u) {
    return __uint_as_float(((unsigned)u) << 16);
}
__device__ __forceinline__ unsigned short f2bf(float f) {
    unsigned u = __float_as_uint(f);
    return (unsigned short)((u + 0x7fffu + ((u >> 16) & 1u)) >> 16);
}
__device__ __forceinline__ void gload_lds16(const void* g, void* l) {
    __builtin_amdgcn_global_load_lds(
        (__attribute__((address_space(1))) void*)g,
        (__attribute__((address_space(3))) void*)l, 16, 0, 0);
}

// fp32 -> bf16 grid-stride convert (vectorized x4)
__global__ __launch_bounds__(256)
void cvt_f32_bf16(const float* __restrict__ src, unsigned short* __restrict__ dst, int n4) {
    int i = blockIdx.x * 256 + threadIdx.x;
    if (i < n4) {
        float4 v = ((const float4*)src)[i];
        ushort4 o;
        o.x = f2bf(v.x); o.y = f2bf(v.y); o.z = f2bf(v.z); o.w = f2bf(v.w);
        ((ushort4*)dst)[i] = o;
    }
}

// RMSNorm over HID=2048, fp32 in -> bf16 out. 1 block per row.
__global__ __launch_bounds__(256)
void rmsnorm_k(const float* __restrict__ x, const float* __restrict__ w,
               unsigned short* __restrict__ out) {
    const int row = blockIdx.x;
    const int tid = threadIdx.x;
    const float4* xr = (const float4*)(x + (size_t)row * kHid);
    float4 v0 = xr[tid];
    float4 v1 = xr[tid + 256];
    float ss = v0.x*v0.x + v0.y*v0.y + v0.z*v0.z + v0.w*v0.w
             + v1.x*v1.x + v1.y*v1.y + v1.z*v1.z + v1.w*v1.w;
#pragma unroll
    for (int m = 1; m < 64; m <<= 1) ss += __shfl_xor(ss, m);
    __shared__ float red[4];
    if ((tid & 63) == 0) red[tid >> 6] = ss;
    __syncthreads();
    float tot = red[0] + red[1] + red[2] + red[3];
    float rs = rsqrtf(tot * (1.0f / kHid) + 1e-6f);
    const float4* wv = (const float4*)w;
    float4 w0 = wv[tid], w1 = wv[tid + 256];
    ushort4 o0, o1;
    o0.x = f2bf(v0.x * rs * w0.x); o0.y = f2bf(v0.y * rs * w0.y);
    o0.z = f2bf(v0.z * rs * w0.z); o0.w = f2bf(v0.w * rs * w0.w);
    o1.x = f2bf(v1.x * rs * w1.x); o1.y = f2bf(v1.y * rs * w1.y);
    o1.z = f2bf(v1.z * rs * w1.z); o1.w = f2bf(v1.w * rs * w1.w);
    ushort4* orow = (ushort4*)(out + (size_t)row * kHid);
    orow[tid] = o0;
    orow[tid + 256] = o1;
}

// GEMM: C(M,N) = A(M,K)bf16 * B(N,K)bf16^T. 128x128 tile, BK=64, 4 waves.
// EPI: 0 = fp32 store, 1 = bf16 store, 2 = fp32 store + Res add,
//      3 = bf16 store of silu(G)*acc
template <int EPI>
__global__ __launch_bounds__(256)
void gemm_bt(const unsigned short* __restrict__ A,
             const unsigned short* __restrict__ B,
             void* __restrict__ C,
             const float* __restrict__ Res,
             const unsigned short* __restrict__ G,
             int M, int N, int K) {
    __shared__ unsigned short As[128 * 64];
    __shared__ unsigned short Bs[128 * 64];

    const int tid  = threadIdx.x;
    const int lane = tid & 63;
    const int l15  = lane & 15;
    const int g4   = lane >> 4;
    const int wid  = tid >> 6;
    const int wr   = wid >> 1;
    const int wc   = wid & 1;
    const int bm   = blockIdx.y * 128;
    const int bn   = blockIdx.x * 128;

    f32x4 acc[4][4] = {};

    for (int k0 = 0; k0 < K; k0 += 64) {
#pragma unroll
        for (int i = 0; i < 4; ++i) {
            int ch  = tid + i * 256;
            int row = ch >> 3;
            int c16 = ch & 7;
            int col = ((c16 ^ (row & 7)) << 3) + k0;
            gload_lds16(A + (size_t)(bm + row) * K + col, (char*)As + ch * 16);
            gload_lds16(B + (size_t)(bn + row) * K + col, (char*)Bs + ch * 16);
        }
        __syncthreads();
#pragma unroll
        for (int ks = 0; ks < 2; ++ks) {
            bf16x8 af[4], bfr[4];
#pragma unroll
            for (int m = 0; m < 4; ++m) {
                int ra = wr * 64 + m * 16 + l15;
                int aa = (ra * 128 + ks * 64 + g4 * 16) ^ ((ra & 7) << 4);
                af[m] = *(const bf16x8*)((const char*)As + aa);
                int rb = wc * 64 + m * 16 + l15;
                int ab = (rb * 128 + ks * 64 + g4 * 16) ^ ((rb & 7) << 4);
                bfr[m] = *(const bf16x8*)((const char*)Bs + ab);
            }
#pragma unroll
            for (int m = 0; m < 4; ++m)
#pragma unroll
                for (int n = 0; n < 4; ++n)
                    acc[m][n] = __builtin_amdgcn_mfma_f32_16x16x32_bf16(
                        af[m], bfr[n], acc[m][n], 0, 0, 0);
        }
        __syncthreads();
    }

#pragma unroll
    for (int m = 0; m < 4; ++m) {
#pragma unroll
        for (int n = 0; n < 4; ++n) {
            int row = bm + wr * 64 + m * 16 + g4 * 4;
            int col = bn + wc * 64 + n * 16 + l15;
#pragma unroll
            for (int r = 0; r < 4; ++r) {
                size_t idx = (size_t)(row + r) * N + col;
                float v = acc[m][n][r];
                if (EPI == 0) {
                    ((float*)C)[idx] = v;
                } else if (EPI == 1) {
                    ((unsigned short*)C)[idx] = f2bf(v);
                } else if (EPI == 2) {
                    ((float*)C)[idx] = v + Res[idx];
                } else {
                    float g = bf2f(G[idx]);
                    ((unsigned short*)C)[idx] = f2bf(g / (1.0f + __expf(-g)) * v);
                }
            }
        }
    }
}

// Fused per-head RMSNorm (D=128) + RoPE for q and k.
__global__ __launch_bounds__(256)
void qknorm_rope(const float* __restrict__ qkv, const int* __restrict__ positions,
                 const float* __restrict__ qnw, const float* __restrict__ knw,
                 unsigned short* __restrict__ Qo, unsigned short* __restrict__ Ko) {
    const int t    = blockIdx.x;
    const int j    = blockIdx.y * 4 + (threadIdx.x >> 6);  // 0..23
    const int lane = threadIdx.x & 63;
    const float* src = qkv + (size_t)t * 4096 + j * 128;
    float x1 = src[lane];
    float x2 = src[lane + 64];
    float ss = x1 * x1 + x2 * x2;
#pragma unroll
    for (int m = 1; m < 64; m <<= 1) ss += __shfl_xor(ss, m);
    float rs = rsqrtf(ss * (1.0f / 128.0f) + 1e-6f);
    const float* w = (j < 16) ? qnw : knw;
    float n1 = x1 * rs * w[lane];
    float n2 = x2 * rs * w[lane + 64];
    float inv = powf(1.0e6f, -(float)lane * (1.0f / 64.0f));
    float fr = (float)positions[t] * inv;
    float sn, cs;
    sincosf(fr, &sn, &cs);
    float o1 = n1 * cs - n2 * sn;
    float o2 = n2 * cs + n1 * sn;
    if (j < 16) {
        unsigned short* d = Qo + (size_t)t * (kH * kD) + j * kD;
        d[lane] = f2bf(o1);
        d[lane + 64] = f2bf(o2);
    } else {
        unsigned short* d = Ko + (size_t)t * (kHK * kD) + (j - 16) * kD;
        d[lane] = f2bf(o1);
        d[lane + 64] = f2bf(o2);
    }
}

// V transpose: qkv fp32 v-part -> Vt bf16 (1024 x T)
__global__ __launch_bounds__(256)
void vtrans(const float* __restrict__ qkv, unsigned short* __restrict__ Vt) {
    __shared__ float tile[32][33];
    const int t0 = blockIdx.x * 32;
    const int d0 = blockIdx.y * 32;
    const int tc = threadIdx.x & 31;
    const int tr = threadIdx.x >> 5;  // 0..7
#pragma unroll
    for (int i = 0; i < 4; ++i) {
        int trow = tr + i * 8;
        tile[trow][tc] = qkv[(size_t)(t0 + trow) * 4096 + 3072 + d0 + tc];
    }
    __syncthreads();
#pragma unroll
    for (int i = 0; i < 4; ++i) {
        int drow = tr + i * 8;
        Vt[(size_t)(d0 + drow) * kT + t0 + tc] = f2bf(tile[tc][drow]);
    }
}

// Causal flash attention v2: 4 waves/block share one kv-head.
// grid (T/32, HK). Wave w: head = by*2 + (w>>1), q0 = bx*32 + (w&1)*16.
// KVBLK=64, K/V staged in LDS (double-buffered, global_load_lds, XOR-swizzled).
__global__ __launch_bounds__(256)
void attn_fwd2(const unsigned short* __restrict__ Q,   // T x (H*D)
               const unsigned short* __restrict__ Kc,  // T x (HK*D)
               const unsigned short* __restrict__ Vt,  // (HK*D) x T
               unsigned short* __restrict__ O) {       // T x (H*D)
    __shared__ unsigned short Ks[2][64 * 128];   // [kv][d], swizzled 16B chunks
    __shared__ unsigned short Vs[2][128 * 64];   // [d][kv], swizzled 16B chunks
    __shared__ unsigned short P_lds[4][16 * 72]; // padded stride 72

    const int tid  = threadIdx.x;
    const int lane = tid & 63;
    const int l15  = lane & 15;
    const int g4   = lane >> 4;
    const int wid  = tid >> 6;
    const int hkk  = blockIdx.y;
    const int h    = hkk * 2 + (wid >> 1);
    const int q0   = blockIdx.x * 32 + (wid & 1) * 16;
    const int nch  = blockIdx.x / 2 + 1;

    bf16x8 qf[4];
#pragma unroll
    for (int ks = 0; ks < 4; ++ks)
        qf[ks] = *(const bf16x8*)(Q + (size_t)(q0 + l15) * (kH * kD) + h * kD + ks * 32 + g4 * 8);

    f32x4 oacc[8] = {};
    float mrow[4] = {-3e38f, -3e38f, -3e38f, -3e38f};
    float lrow[4] = {0.f, 0.f, 0.f, 0.f};
    const float scale = 0.08838834764831845f;  // 1/sqrt(128)

    auto stage = [&](int b, int kv0) {
#pragma unroll
        for (int i = 0; i < 4; ++i) {
            int ch  = tid + i * 256;
            int row = ch >> 4;
            int c16 = ch & 15;
            gload_lds16(Kc + (size_t)(kv0 + row) * (kHK * kD) + hkk * kD
                            + ((c16 ^ (row & 7)) * 8),
                        (char*)Ks[b] + ch * 16);
        }
#pragma unroll
        for (int i = 0; i < 4; ++i) {
            int ch  = tid + i * 256;
            int row = ch >> 3;
            int c8  = ch & 7;
            gload_lds16(Vt + (size_t)(hkk * kD + row) * kT + kv0
                            + ((c8 ^ (row & 7)) * 8),
                        (char*)Vs[b] + ch * 16);
        }
    };

    stage(0, 0);
    __syncthreads();

    for (int c = 0; c < nch; ++c) {
        const int kv0 = c * 64;
        const int b   = c & 1;
        if (c + 1 < nch) stage(b ^ 1, kv0 + 64);

        if (kv0 <= q0 + 15) {
            // ---- QK^T: S[16q x 64kv] ----
            f32x4 s[4] = {};
#pragma unroll
            for (int half = 0; half < 4; ++half) {
                const int row = half * 16 + l15;
#pragma unroll
                for (int ks = 0; ks < 4; ++ks) {
                    bf16x8 kf = *(const bf16x8*)((const char*)Ks[b]
                                  + row * 256 + (((ks * 4 + g4) ^ (row & 7)) * 16));
                    s[half] = __builtin_amdgcn_mfma_f32_16x16x32_bf16(qf[ks], kf, s[half], 0, 0, 0);
                }
            }
            // ---- mask + online softmax ----
            float pv[4][4];
#pragma unroll
            for (int half = 0; half < 4; ++half)
#pragma unroll
                for (int r = 0; r < 4; ++r) {
                    float v = s[half][r] * scale;
                    int qi = q0 + g4 * 4 + r;
                    int ki = kv0 + half * 16 + l15;
                    pv[half][r] = (ki > qi) ? -3e38f : v;
                }
#pragma unroll
            for (int r = 0; r < 4; ++r) {
                float rm = fmaxf(fmaxf(pv[0][r], pv[1][r]), fmaxf(pv[2][r], pv[3][r]));
#pragma unroll
                for (int msk = 1; msk < 16; msk <<= 1)
                    rm = fmaxf(rm, __shfl_xor(rm, msk));
                float mnew = fmaxf(mrow[r], rm);
                float corr = __expf(mrow[r] - mnew);
                mrow[r] = mnew;
                lrow[r] *= corr;
#pragma unroll
                for (int c2 = 0; c2 < 8; ++c2)
                    oacc[c2][r] *= corr;
                float ps = 0.f;
#pragma unroll
                for (int half = 0; half < 4; ++half) {
                    float p = __expf(pv[half][r] - mnew);
                    ps += p;
                    P_lds[wid][(g4 * 4 + r) * 72 + half * 16 + l15] = f2bf(p);
                }
#pragma unroll
                for (int msk = 1; msk < 16; msk <<= 1)
                    ps += __shfl_xor(ps, msk);
                lrow[r] += ps;
            }
            asm volatile("s_waitcnt lgkmcnt(0)" ::: "memory");
            __builtin_amdgcn_sched_barrier(0);
            // ---- PV ----
            bf16x8 pa[2];
#pragma unroll
            for (int ks2 = 0; ks2 < 2; ++ks2)
                pa[ks2] = *(const bf16x8*)(&P_lds[wid][l15 * 72 + ks2 * 32 + g4 * 8]);
#pragma unroll
            for (int c2 = 0; c2 < 8; ++c2) {
                const int d = c2 * 16 + l15;
#pragma unroll
                for (int ks2 = 0; ks2 < 2; ++ks2) {
                    bf16x8 vf = *(const bf16x8*)((const char*)Vs[b]
                                  + d * 128 + (((ks2 * 4 + g4) ^ (d & 7)) * 16));
                    oacc[c2] = __builtin_amdgcn_mfma_f32_16x16x32_bf16(pa[ks2], vf, oacc[c2], 0, 0, 0);
                }
            }
        }
        __syncthreads();
    }

#pragma unroll
    for (int c2 = 0; c2 < 8; ++c2)
#pragma unroll
        for (int r = 0; r < 4; ++r) {
            float v = oacc[c2][r] / lrow[r];
            O[(size_t)(q0 + g4 * 4 + r) * (kH * kD) + h * kD + c2 * 16 + l15] = f2bf(v);
        }
}

}  // namespace

extern "C" void kernel_launch(void* const* d_in, const int* in_sizes, int n_in,
                              void* d_out, int out_size, void* d_ws, size_t ws_size,
                              hipStream_t stream) {
    (void)in_sizes; (void)n_in; (void)out_size; (void)ws_size;

    const int*   positions = (const int*)  d_in[0];
    const float* hidden    = (const float*)d_in[1];
    const float* wq  = (const float*)d_in[2];
    const float* wk  = (const float*)d_in[3];
    const float* wv  = (const float*)d_in[4];
    const float* wo  = (const float*)d_in[5];
    const float* qnw = (const float*)d_in[6];
    const float* knw = (const float*)d_in[7];
    const float* ln1 = (const float*)d_in[8];
    const float* ln2 = (const float*)d_in[9];
    const float* wg  = (const float*)d_in[10];
    const float* wu  = (const float*)d_in[11];
    const float* wd  = (const float*)d_in[12];

    char* ws = (char*)d_ws;
    unsigned short* WQKV = (unsigned short*)(ws + 0);          // 4096x2048 bf16
    unsigned short* WO   = (unsigned short*)(ws + 16777216);   // 2048x2048
    unsigned short* WG   = (unsigned short*)(ws + 25165824);   // 6144x2048
    unsigned short* WU   = (unsigned short*)(ws + 50331648);   // 6144x2048
    unsigned short* WD   = (unsigned short*)(ws + 75497472);   // 2048x6144
    unsigned short* XN1  = (unsigned short*)(ws + 100663296);  // T x 2048
    unsigned short* OATT = (unsigned short*)(ws + 109051904);  // T x 2048
    float*          H1   = (float*)(ws + 117440512);           // T x 2048 fp32
    unsigned short* XN2  = (unsigned short*)(ws + 134217728);  // T x 2048
    float*          QKVF = (float*)(ws + 142606336);           // T x 4096 fp32
    unsigned short* QB   = (unsigned short*)(ws + 176160768);  // T x 2048
    unsigned short* KB   = (unsigned short*)(ws + 184549376);  // T x 1024
    unsigned short* VT   = (unsigned short*)(ws + 188743680);  // 1024 x T
    unsigned short* GATE = (unsigned short*)(ws + 142606336);  // T x 6144 (alias)
    unsigned short* ACT  = (unsigned short*)(ws + 167772160);  // T x 6144 (alias)

    auto cvt = [&](const float* s, unsigned short* dst, size_t n) {
        int n4 = (int)(n / 4);
        cvt_f32_bf16<<<dim3((n4 + 255) / 256), dim3(256), 0, stream>>>(s, dst, n4);
    };

    cvt(wq, WQKV,                 (size_t)kH  * kD * kHid);
    cvt(wk, WQKV + 2048 * kHid,   (size_t)kHK * kD * kHid);
    cvt(wv, WQKV + 3072 * kHid,   (size_t)kHK * kD * kHid);
    cvt(wo, WO,                   (size_t)kHid * kH * kD);
    cvt(wg, WG,                   (size_t)kFF * kHid);
    cvt(wu, WU,                   (size_t)kFF * kHid);
    cvt(wd, WD,                   (size_t)kHid * kFF);

    rmsnorm_k<<<dim3(kT), dim3(256), 0, stream>>>(hidden, ln1, XN1);

    gemm_bt<0><<<dim3(4096 / 128, kT / 128), dim3(256), 0, stream>>>(
        XN1, WQKV, QKVF, nullptr, nullptr, kT, 4096, kHid);

    qknorm_rope<<<dim3(kT, 6), dim3(256), 0, stream>>>(QKVF, positions, qnw, knw, QB, KB);

    vtrans<<<dim3(kT / 32, 1024 / 32), dim3(256), 0, stream>>>(QKVF, VT);

    attn_fwd2<<<dim3(kT / 32, kHK), dim3(256), 0, stream>>>(QB, KB, VT, OATT);

    gemm_bt<2><<<dim3(kHid / 128, kT / 128), dim3(256), 0, stream>>>(
        OATT, WO, H1, hidden, nullptr, kT, kHid, kHid);

    rmsnorm_k<<<dim3(kT), dim3(256), 0, stream>>>(H1, ln2, XN2);

    gemm_bt<1><<<dim3(kFF / 128, kT / 128), dim3(256), 0, stream>>>(
        XN2, WG, GATE, nullptr, nullptr, kT, kFF, kHid);

    gemm_bt<3><<<dim3(kFF / 128, kT / 128), dim3(256), 0, stream>>>(
        XN2, WU, ACT, nullptr, GATE, kT, kFF, kHid);

    gemm_bt<2><<<dim3(kHid / 128, kT / 128), dim3(256), 0, stream>>>(
        ACT, WD, (float*)d_out, H1, nullptr, kT, kHid, kFF);
}

// Round 3
// 550.388 us; speedup vs baseline: 1.3206x; 1.0775x over previous
//
#include <hip/hip_runtime.h>
#include <hip/hip_bf16.h>
#include <stdint.h>

namespace {

constexpr int kT   = 2048;
constexpr int kHid = 2048;
constexpr int kH   = 16;
constexpr int kHK  = 8;
constexpr int kD   = 128;
constexpr int kFF  = 6144;

using bf16x8 = __attribute__((ext_vector_type(8))) short;
using f32x4  = __attribute__((ext_vector_type(4))) float;

__device__ __forceinline__ float bf2f(unsigned short u) {
    return __uint_as_float(((unsigned)u) << 16);
}
__device__ __forceinline__ unsigned short f2bf(float f) {
    unsigned u = __float_as_uint(f);
    return (unsigned short)((u + 0x7fffu + ((u >> 16) & 1u)) >> 16);
}
__device__ __forceinline__ void gload_lds16(const void* g, void* l) {
    __builtin_amdgcn_global_load_lds(
        (__attribute__((address_space(1))) void*)g,
        (__attribute__((address_space(3))) void*)l, 16, 0, 0);
}
__device__ __forceinline__ f32x4 mf(bf16x8 a, bf16x8 b, f32x4 c) {
    return __builtin_amdgcn_mfma_f32_16x16x32_bf16(a, b, c, 0, 0, 0);
}

// fp32 -> bf16 grid-stride convert (vectorized x4)
__global__ __launch_bounds__(256)
void cvt_f32_bf16(const float* __restrict__ src, unsigned short* __restrict__ dst, int n4) {
    int i = blockIdx.x * 256 + threadIdx.x;
    if (i < n4) {
        float4 v = ((const float4*)src)[i];
        ushort4 o;
        o.x = f2bf(v.x); o.y = f2bf(v.y); o.z = f2bf(v.z); o.w = f2bf(v.w);
        ((ushort4*)dst)[i] = o;
    }
}

// RMSNorm over HID=2048, fp32 in -> bf16 out. 1 block per row.
__global__ __launch_bounds__(256)
void rmsnorm_k(const float* __restrict__ x, const float* __restrict__ w,
               unsigned short* __restrict__ out) {
    const int row = blockIdx.x;
    const int tid = threadIdx.x;
    const float4* xr = (const float4*)(x + (size_t)row * kHid);
    float4 v0 = xr[tid];
    float4 v1 = xr[tid + 256];
    float ss = v0.x*v0.x + v0.y*v0.y + v0.z*v0.z + v0.w*v0.w
             + v1.x*v1.x + v1.y*v1.y + v1.z*v1.z + v1.w*v1.w;
#pragma unroll
    for (int m = 1; m < 64; m <<= 1) ss += __shfl_xor(ss, m);
    __shared__ float red[4];
    if ((tid & 63) == 0) red[tid >> 6] = ss;
    __syncthreads();
    float tot = red[0] + red[1] + red[2] + red[3];
    float rs = rsqrtf(tot * (1.0f / kHid) + 1e-6f);
    const float4* wv = (const float4*)w;
    float4 w0 = wv[tid], w1 = wv[tid + 256];
    ushort4 o0, o1;
    o0.x = f2bf(v0.x * rs * w0.x); o0.y = f2bf(v0.y * rs * w0.y);
    o0.z = f2bf(v0.z * rs * w0.z); o0.w = f2bf(v0.w * rs * w0.w);
    o1.x = f2bf(v1.x * rs * w1.x); o1.y = f2bf(v1.y * rs * w1.y);
    o1.z = f2bf(v1.z * rs * w1.z); o1.w = f2bf(v1.w * rs * w1.w);
    ushort4* orow = (ushort4*)(out + (size_t)row * kHid);
    orow[tid] = o0;
    orow[tid + 256] = o1;
}

// -------- 128x128 1-phase GEMM (kept for O-proj / down) --------
// EPI: 0 = fp32 store, 1 = bf16 store, 2 = fp32 store + Res add,
//      3 = bf16 store of silu(G)*acc
template <int EPI>
__global__ __launch_bounds__(256)
void gemm_bt(const unsigned short* __restrict__ A,
             const unsigned short* __restrict__ B,
             void* __restrict__ C,
             const float* __restrict__ Res,
             const unsigned short* __restrict__ G,
             int M, int N, int K) {
    __shared__ unsigned short As[128 * 64];
    __shared__ unsigned short Bs[128 * 64];

    const int tid  = threadIdx.x;
    const int lane = tid & 63;
    const int l15  = lane & 15;
    const int g4   = lane >> 4;
    const int wid  = tid >> 6;
    const int wr   = wid >> 1;
    const int wc   = wid & 1;
    const int bm   = blockIdx.y * 128;
    const int bn   = blockIdx.x * 128;

    f32x4 acc[4][4] = {};

    for (int k0 = 0; k0 < K; k0 += 64) {
#pragma unroll
        for (int i = 0; i < 4; ++i) {
            int ch  = tid + i * 256;
            int row = ch >> 3;
            int c16 = ch & 7;
            int col = ((c16 ^ (row & 7)) << 3) + k0;
            gload_lds16(A + (size_t)(bm + row) * K + col, (char*)As + ch * 16);
            gload_lds16(B + (size_t)(bn + row) * K + col, (char*)Bs + ch * 16);
        }
        __syncthreads();
#pragma unroll
        for (int ks = 0; ks < 2; ++ks) {
            bf16x8 af[4], bfr[4];
#pragma unroll
            for (int m = 0; m < 4; ++m) {
                int ra = wr * 64 + m * 16 + l15;
                int aa = (ra * 128 + ks * 64 + g4 * 16) ^ ((ra & 7) << 4);
                af[m] = *(const bf16x8*)((const char*)As + aa);
                int rb = wc * 64 + m * 16 + l15;
                int ab = (rb * 128 + ks * 64 + g4 * 16) ^ ((rb & 7) << 4);
                bfr[m] = *(const bf16x8*)((const char*)Bs + ab);
            }
#pragma unroll
            for (int m = 0; m < 4; ++m)
#pragma unroll
                for (int n = 0; n < 4; ++n)
                    acc[m][n] = mf(af[m], bfr[n], acc[m][n]);
        }
        __syncthreads();
    }

#pragma unroll
    for (int m = 0; m < 4; ++m) {
#pragma unroll
        for (int n = 0; n < 4; ++n) {
            int row = bm + wr * 64 + m * 16 + g4 * 4;
            int col = bn + wc * 64 + n * 16 + l15;
#pragma unroll
            for (int r = 0; r < 4; ++r) {
                size_t idx = (size_t)(row + r) * N + col;
                float v = acc[m][n][r];
                if (EPI == 0) {
                    ((float*)C)[idx] = v;
                } else if (EPI == 1) {
                    ((unsigned short*)C)[idx] = f2bf(v);
                } else if (EPI == 2) {
                    ((float*)C)[idx] = v + Res[idx];
                } else {
                    float g = bf2f(G[idx]);
                    ((unsigned short*)C)[idx] = f2bf(g / (1.0f + __expf(-g)) * v);
                }
            }
        }
    }
}

// -------- 256x256 8-phase GEMM (T2+T3+T4+T5 template) --------
// 512 threads = 8 waves (2M x 4N), BK=64, 2 K-tiles per iteration.
// LDS 128 KiB: smem[buf][region][128*64], region 0/1 = A half 0/1 (rows),
// region 2/3 = B half 0/1. Counted vmcnt(6), never drained in main loop.
template <int EPI>
__global__ __launch_bounds__(512, 2)
void gemm256(const unsigned short* __restrict__ A,
             const unsigned short* __restrict__ B,
             void* __restrict__ C,
             const float* __restrict__ Res,
             const unsigned short* __restrict__ G,
             int M, int N, int K) {
    __shared__ unsigned short smem[2][4][128 * 64];  // 128 KiB

    const int tid  = threadIdx.x;
    const int lane = tid & 63;
    const int l15  = lane & 15;
    const int g4   = lane >> 4;
    const int wid  = tid >> 6;   // 0..7
    const int wr   = wid >> 2;   // 0..1  (M half)
    const int wc   = wid & 3;    // 0..3  (N quarter)
    const int bm   = blockIdx.y * 256;
    const int bn   = blockIdx.x * 256;
    const int NT   = K >> 6;
    const int NI   = NT >> 1;

    f32x4 acc[8][4] = {};

    // stage one 16KB half-tile (2 gload_lds x 512 threads).
    // linear LDS dest + inverse-swizzled global source (guide rule 21).
    auto stage = [&](int b, int reg, int t) {
        const unsigned short* Base = (reg < 2) ? A : B;
        const int br = ((reg < 2) ? bm : bn) + (reg & 1) * 128;
#pragma unroll
        for (int i = 0; i < 2; ++i) {
            int ch   = tid + i * 512;
            int row  = ch >> 3;
            int slot = (ch & 7) ^ (row & 7);
            gload_lds16(Base + (size_t)(br + row) * K + t * 64 + slot * 8,
                        (char*)&smem[b][reg][0] + ch * 16);
        }
    };
    auto rdA = [&](int b, int m, int ks) {
        int row = m * 16 + l15;
        return *(const bf16x8*)((const char*)&smem[b][wr][0]
               + row * 128 + (((ks * 4 + g4) ^ (row & 7)) * 16));
    };
    auto rdB = [&](int b, int n, int ks) {
        int row = wc * 64 + n * 16 + l15;   // 0..255 within N-tile
        return *(const bf16x8*)((const char*)&smem[b][2 + (row >> 7)][0]
               + (row & 127) * 128 + (((ks * 4 + g4) ^ (row & 7)) * 16));
    };

    // prologue: tile0 {Bh0,Bh1,Ah0,Ah1} -> buf0; tile1 {Bh0,Bh1,Ah0} -> buf1 (14 loads)
    stage(0, 2, 0); stage(0, 3, 0); stage(0, 0, 0); stage(0, 1, 0);
    stage(1, 2, 1); stage(1, 3, 1); stage(1, 0, 1);
    asm volatile("s_waitcnt vmcnt(6)" ::: "memory");
    __builtin_amdgcn_s_barrier();

    for (int i = 0; i < NI; ++i) {
        const int e  = 2 * i;
        const int o  = e + 1;
        const bool pf = (e + 2 < NT);
        bf16x8 af[4][2], bfr[4][2];

        // ---- P1: read all B + A(m0-3) of tile e (buf0); stage Ah1(o)->buf1 ----
#pragma unroll
        for (int m = 0; m < 4; ++m) { af[m][0] = rdA(0, m, 0); af[m][1] = rdA(0, m, 1); }
#pragma unroll
        for (int n = 0; n < 4; ++n) { bfr[n][0] = rdB(0, n, 0); bfr[n][1] = rdB(0, n, 1); }
        stage(1, 1, o);
        __builtin_amdgcn_s_barrier();
        asm volatile("s_waitcnt lgkmcnt(0)" ::: "memory");
        __builtin_amdgcn_sched_barrier(0);
        __builtin_amdgcn_s_setprio(1);
#pragma unroll
        for (int m = 0; m < 4; ++m)
#pragma unroll
            for (int n = 0; n < 2; ++n) {
                acc[m][n] = mf(af[m][0], bfr[n][0], acc[m][n]);
                acc[m][n] = mf(af[m][1], bfr[n][1], acc[m][n]);
            }
        __builtin_amdgcn_s_setprio(0);
        __builtin_amdgcn_s_barrier();

        // ---- P2: stage Bh0(e+2)->buf0; MFMA m0-3 x n2-3 ----
        if (pf) stage(0, 2, e + 2);
        __builtin_amdgcn_s_barrier();
        __builtin_amdgcn_s_setprio(1);
#pragma unroll
        for (int m = 0; m < 4; ++m)
#pragma unroll
            for (int n = 2; n < 4; ++n) {
                acc[m][n] = mf(af[m][0], bfr[n][0], acc[m][n]);
                acc[m][n] = mf(af[m][1], bfr[n][1], acc[m][n]);
            }
        __builtin_amdgcn_s_setprio(0);
        __builtin_amdgcn_s_barrier();

        // ---- P3: read A(m4-7) tile e; stage Bh1(e+2)->buf0; MFMA m4-7 x n0-1 ----
#pragma unroll
        for (int m = 0; m < 4; ++m) { af[m][0] = rdA(0, 4 + m, 0); af[m][1] = rdA(0, 4 + m, 1); }
        if (pf) stage(0, 3, e + 2);
        __builtin_amdgcn_s_barrier();
        asm volatile("s_waitcnt lgkmcnt(0)" ::: "memory");
        __builtin_amdgcn_sched_barrier(0);
        __builtin_amdgcn_s_setprio(1);
#pragma unroll
        for (int m = 0; m < 4; ++m)
#pragma unroll
            for (int n = 0; n < 2; ++n) {
                acc[4 + m][n] = mf(af[m][0], bfr[n][0], acc[4 + m][n]);
                acc[4 + m][n] = mf(af[m][1], bfr[n][1], acc[4 + m][n]);
            }
        __builtin_amdgcn_s_setprio(0);
        __builtin_amdgcn_s_barrier();

        // ---- P4: stage Ah0(e+2)->buf0; MFMA m4-7 x n2-3; vmcnt gate for tile o ----
        if (pf) stage(0, 0, e + 2);
        __builtin_amdgcn_s_barrier();
        __builtin_amdgcn_s_setprio(1);
#pragma unroll
        for (int m = 0; m < 4; ++m)
#pragma unroll
            for (int n = 2; n < 4; ++n) {
                acc[4 + m][n] = mf(af[m][0], bfr[n][0], acc[4 + m][n]);
                acc[4 + m][n] = mf(af[m][1], bfr[n][1], acc[4 + m][n]);
            }
        __builtin_amdgcn_s_setprio(0);
        if (pf) asm volatile("s_waitcnt vmcnt(6)" ::: "memory");
        else    asm volatile("s_waitcnt vmcnt(0)" ::: "memory");
        __builtin_amdgcn_s_barrier();

        // ---- P5: read all B + A(m0-3) of tile o (buf1); stage Ah1(e+2)->buf0 ----
#pragma unroll
        for (int m = 0; m < 4; ++m) { af[m][0] = rdA(1, m, 0); af[m][1] = rdA(1, m, 1); }
#pragma unroll
        for (int n = 0; n < 4; ++n) { bfr[n][0] = rdB(1, n, 0); bfr[n][1] = rdB(1, n, 1); }
        if (pf) stage(0, 1, e + 2);
        __builtin_amdgcn_s_barrier();
        asm volatile("s_waitcnt lgkmcnt(0)" ::: "memory");
        __builtin_amdgcn_sched_barrier(0);
        __builtin_amdgcn_s_setprio(1);
#pragma unroll
        for (int m = 0; m < 4; ++m)
#pragma unroll
            for (int n = 0; n < 2; ++n) {
                acc[m][n] = mf(af[m][0], bfr[n][0], acc[m][n]);
                acc[m][n] = mf(af[m][1], bfr[n][1], acc[m][n]);
            }
        __builtin_amdgcn_s_setprio(0);
        __builtin_amdgcn_s_barrier();

        // ---- P6: stage Bh0(o+2)->buf1; MFMA m0-3 x n2-3 ----
        if (pf) stage(1, 2, o + 2);
        __builtin_amdgcn_s_barrier();
        __builtin_amdgcn_s_setprio(1);
#pragma unroll
        for (int m = 0; m < 4; ++m)
#pragma unroll
            for (int n = 2; n < 4; ++n) {
                acc[m][n] = mf(af[m][0], bfr[n][0], acc[m][n]);
                acc[m][n] = mf(af[m][1], bfr[n][1], acc[m][n]);
            }
        __builtin_amdgcn_s_setprio(0);
        __builtin_amdgcn_s_barrier();

        // ---- P7: read A(m4-7) tile o; stage Bh1(o+2)->buf1; MFMA m4-7 x n0-1 ----
#pragma unroll
        for (int m = 0; m < 4; ++m) { af[m][0] = rdA(1, 4 + m, 0); af[m][1] = rdA(1, 4 + m, 1); }
        if (pf) stage(1, 3, o + 2);
        __builtin_amdgcn_s_barrier();
        asm volatile("s_waitcnt lgkmcnt(0)" ::: "memory");
        __builtin_amdgcn_sched_barrier(0);
        __builtin_amdgcn_s_setprio(1);
#pragma unroll
        for (int m = 0; m < 4; ++m)
#pragma unroll
            for (int n = 0; n < 2; ++n) {
                acc[4 + m][n] = mf(af[m][0], bfr[n][0], acc[4 + m][n]);
                acc[4 + m][n] = mf(af[m][1], bfr[n][1], acc[4 + m][n]);
            }
        __builtin_amdgcn_s_setprio(0);
        __builtin_amdgcn_s_barrier();

        // ---- P8: stage Ah0(o+2)->buf1; MFMA m4-7 x n2-3; vmcnt gate for tile e+2 ----
        if (pf) stage(1, 0, o + 2);
        __builtin_amdgcn_s_barrier();
        __builtin_amdgcn_s_setprio(1);
#pragma unroll
        for (int m = 0; m < 4; ++m)
#pragma unroll
            for (int n = 2; n < 4; ++n) {
                acc[4 + m][n] = mf(af[m][0], bfr[n][0], acc[4 + m][n]);
                acc[4 + m][n] = mf(af[m][1], bfr[n][1], acc[4 + m][n]);
            }
        __builtin_amdgcn_s_setprio(0);
        if (pf) asm volatile("s_waitcnt vmcnt(6)" ::: "memory");
        __builtin_amdgcn_s_barrier();
    }

    // epilogue
#pragma unroll
    for (int m = 0; m < 8; ++m) {
#pragma unroll
        for (int n = 0; n < 4; ++n) {
            int row = bm + wr * 128 + m * 16 + g4 * 4;
            int col = bn + wc * 64 + n * 16 + l15;
#pragma unroll
            for (int r = 0; r < 4; ++r) {
                size_t idx = (size_t)(row + r) * N + col;
                float v = acc[m][n][r];
                if (EPI == 0) {
                    ((float*)C)[idx] = v;
                } else if (EPI == 1) {
                    ((unsigned short*)C)[idx] = f2bf(v);
                } else if (EPI == 2) {
                    ((float*)C)[idx] = v + Res[idx];
                } else {
                    float g = bf2f(G[idx]);
                    ((unsigned short*)C)[idx] = f2bf(g / (1.0f + __expf(-g)) * v);
                }
            }
        }
    }
}

// Fused per-head RMSNorm (D=128) + RoPE for q and k.
__global__ __launch_bounds__(256)
void qknorm_rope(const float* __restrict__ qkv, const int* __restrict__ positions,
                 const float* __restrict__ qnw, const float* __restrict__ knw,
                 unsigned short* __restrict__ Qo, unsigned short* __restrict__ Ko) {
    const int t    = blockIdx.x;
    const int j    = blockIdx.y * 4 + (threadIdx.x >> 6);  // 0..23
    const int lane = threadIdx.x & 63;
    const float* src = qkv + (size_t)t * 4096 + j * 128;
    float x1 = src[lane];
    float x2 = src[lane + 64];
    float ss = x1 * x1 + x2 * x2;
#pragma unroll
    for (int m = 1; m < 64; m <<= 1) ss += __shfl_xor(ss, m);
    float rs = rsqrtf(ss * (1.0f / 128.0f) + 1e-6f);
    const float* w = (j < 16) ? qnw : knw;
    float n1 = x1 * rs * w[lane];
    float n2 = x2 * rs * w[lane + 64];
    float inv = powf(1.0e6f, -(float)lane * (1.0f / 64.0f));
    float fr = (float)positions[t] * inv;
    float sn, cs;
    sincosf(fr, &sn, &cs);
    float o1 = n1 * cs - n2 * sn;
    float o2 = n2 * cs + n1 * sn;
    if (j < 16) {
        unsigned short* d = Qo + (size_t)t * (kH * kD) + j * kD;
        d[lane] = f2bf(o1);
        d[lane + 64] = f2bf(o2);
    } else {
        unsigned short* d = Ko + (size_t)t * (kHK * kD) + (j - 16) * kD;
        d[lane] = f2bf(o1);
        d[lane + 64] = f2bf(o2);
    }
}

// V transpose: qkv fp32 v-part -> Vt bf16 (1024 x T)
__global__ __launch_bounds__(256)
void vtrans(const float* __restrict__ qkv, unsigned short* __restrict__ Vt) {
    __shared__ float tile[32][33];
    const int t0 = blockIdx.x * 32;
    const int d0 = blockIdx.y * 32;
    const int tc = threadIdx.x & 31;
    const int tr = threadIdx.x >> 5;  // 0..7
#pragma unroll
    for (int i = 0; i < 4; ++i) {
        int trow = tr + i * 8;
        tile[trow][tc] = qkv[(size_t)(t0 + trow) * 4096 + 3072 + d0 + tc];
    }
    __syncthreads();
#pragma unroll
    for (int i = 0; i < 4; ++i) {
        int drow = tr + i * 8;
        Vt[(size_t)(d0 + drow) * kT + t0 + tc] = f2bf(tile[tc][drow]);
    }
}

// Causal flash attention: 4 waves/block share one kv-head, KVBLK=64,
// K/V staged in LDS (double-buffered, global_load_lds, XOR-swizzled).
__global__ __launch_bounds__(256)
void attn_fwd2(const unsigned short* __restrict__ Q,   // T x (H*D)
               const unsigned short* __restrict__ Kc,  // T x (HK*D)
               const unsigned short* __restrict__ Vt,  // (HK*D) x T
               unsigned short* __restrict__ O) {       // T x (H*D)
    __shared__ unsigned short Ks[2][64 * 128];
    __shared__ unsigned short Vs[2][128 * 64];
    __shared__ unsigned short P_lds[4][16 * 72];

    const int tid  = threadIdx.x;
    const int lane = tid & 63;
    const int l15  = lane & 15;
    const int g4   = lane >> 4;
    const int wid  = tid >> 6;
    const int hkk  = blockIdx.y;
    const int h    = hkk * 2 + (wid >> 1);
    const int q0   = blockIdx.x * 32 + (wid & 1) * 16;
    const int nch  = blockIdx.x / 2 + 1;

    bf16x8 qf[4];
#pragma unroll
    for (int ks = 0; ks < 4; ++ks)
        qf[ks] = *(const bf16x8*)(Q + (size_t)(q0 + l15) * (kH * kD) + h * kD + ks * 32 + g4 * 8);

    f32x4 oacc[8] = {};
    float mrow[4] = {-3e38f, -3e38f, -3e38f, -3e38f};
    float lrow[4] = {0.f, 0.f, 0.f, 0.f};
    const float scale = 0.08838834764831845f;  // 1/sqrt(128)

    auto stage = [&](int b, int kv0) {
#pragma unroll
        for (int i = 0; i < 4; ++i) {
            int ch  = tid + i * 256;
            int row = ch >> 4;
            int c16 = ch & 15;
            gload_lds16(Kc + (size_t)(kv0 + row) * (kHK * kD) + hkk * kD
                            + ((c16 ^ (row & 7)) * 8),
                        (char*)Ks[b] + ch * 16);
        }
#pragma unroll
        for (int i = 0; i < 4; ++i) {
            int ch  = tid + i * 256;
            int row = ch >> 3;
            int c8  = ch & 7;
            gload_lds16(Vt + (size_t)(hkk * kD + row) * kT + kv0
                            + ((c8 ^ (row & 7)) * 8),
                        (char*)Vs[b] + ch * 16);
        }
    };

    stage(0, 0);
    __syncthreads();

    for (int c = 0; c < nch; ++c) {
        const int kv0 = c * 64;
        const int b   = c & 1;
        if (c + 1 < nch) stage(b ^ 1, kv0 + 64);

        if (kv0 <= q0 + 15) {
            f32x4 s[4] = {};
#pragma unroll
            for (int half = 0; half < 4; ++half) {
                const int row = half * 16 + l15;
#pragma unroll
                for (int ks = 0; ks < 4; ++ks) {
                    bf16x8 kf = *(const bf16x8*)((const char*)Ks[b]
                                  + row * 256 + (((ks * 4 + g4) ^ (row & 7)) * 16));
                    s[half] = mf(qf[ks], kf, s[half]);
                }
            }
            float pv[4][4];
#pragma unroll
            for (int half = 0; half < 4; ++half)
#pragma unroll
                for (int r = 0; r < 4; ++r) {
                    float v = s[half][r] * scale;
                    int qi = q0 + g4 * 4 + r;
                    int ki = kv0 + half * 16 + l15;
                    pv[half][r] = (ki > qi) ? -3e38f : v;
                }
#pragma unroll
            for (int r = 0; r < 4; ++r) {
                float rm = fmaxf(fmaxf(pv[0][r], pv[1][r]), fmaxf(pv[2][r], pv[3][r]));
#pragma unroll
                for (int msk = 1; msk < 16; msk <<= 1)
                    rm = fmaxf(rm, __shfl_xor(rm, msk));
                float mnew = fmaxf(mrow[r], rm);
                float corr = __expf(mrow[r] - mnew);
                mrow[r] = mnew;
                lrow[r] *= corr;
#pragma unroll
                for (int c2 = 0; c2 < 8; ++c2)
                    oacc[c2][r] *= corr;
                float ps = 0.f;
#pragma unroll
                for (int half = 0; half < 4; ++half) {
                    float p = __expf(pv[half][r] - mnew);
                    ps += p;
                    P_lds[wid][(g4 * 4 + r) * 72 + half * 16 + l15] = f2bf(p);
                }
#pragma unroll
                for (int msk = 1; msk < 16; msk <<= 1)
                    ps += __shfl_xor(ps, msk);
                lrow[r] += ps;
            }
            asm volatile("s_waitcnt lgkmcnt(0)" ::: "memory");
            __builtin_amdgcn_sched_barrier(0);
            bf16x8 pa[2];
#pragma unroll
            for (int ks2 = 0; ks2 < 2; ++ks2)
                pa[ks2] = *(const bf16x8*)(&P_lds[wid][l15 * 72 + ks2 * 32 + g4 * 8]);
#pragma unroll
            for (int c2 = 0; c2 < 8; ++c2) {
                const int d = c2 * 16 + l15;
#pragma unroll
                for (int ks2 = 0; ks2 < 2; ++ks2) {
                    bf16x8 vf = *(const bf16x8*)((const char*)Vs[b]
                                  + d * 128 + (((ks2 * 4 + g4) ^ (d & 7)) * 16));
                    oacc[c2] = mf(pa[ks2], vf, oacc[c2]);
                }
            }
        }
        __syncthreads();
    }

#pragma unroll
    for (int c2 = 0; c2 < 8; ++c2)
#pragma unroll
        for (int r = 0; r < 4; ++r) {
            float v = oacc[c2][r] / lrow[r];
            O[(size_t)(q0 + g4 * 4 + r) * (kH * kD) + h * kD + c2 * 16 + l15] = f2bf(v);
        }
}

}  // namespace

extern "C" void kernel_launch(void* const* d_in, const int* in_sizes, int n_in,
                              void* d_out, int out_size, void* d_ws, size_t ws_size,
                              hipStream_t stream) {
    (void)in_sizes; (void)n_in; (void)out_size; (void)ws_size;

    const int*   positions = (const int*)  d_in[0];
    const float* hidden    = (const float*)d_in[1];
    const float* wq  = (const float*)d_in[2];
    const float* wk  = (const float*)d_in[3];
    const float* wv  = (const float*)d_in[4];
    const float* wo  = (const float*)d_in[5];
    const float* qnw = (const float*)d_in[6];
    const float* knw = (const float*)d_in[7];
    const float* ln1 = (const float*)d_in[8];
    const float* ln2 = (const float*)d_in[9];
    const float* wg  = (const float*)d_in[10];
    const float* wu  = (const float*)d_in[11];
    const float* wd  = (const float*)d_in[12];

    char* ws = (char*)d_ws;
    unsigned short* WQKV = (unsigned short*)(ws + 0);          // 4096x2048 bf16
    unsigned short* WO   = (unsigned short*)(ws + 16777216);   // 2048x2048
    unsigned short* WG   = (unsigned short*)(ws + 25165824);   // 6144x2048
    unsigned short* WU   = (unsigned short*)(ws + 50331648);   // 6144x2048
    unsigned short* WD   = (unsigned short*)(ws + 75497472);   // 2048x6144
    unsigned short* XN1  = (unsigned short*)(ws + 100663296);  // T x 2048
    unsigned short* OATT = (unsigned short*)(ws + 109051904);  // T x 2048
    float*          H1   = (float*)(ws + 117440512);           // T x 2048 fp32
    unsigned short* XN2  = (unsigned short*)(ws + 134217728);  // T x 2048
    float*          QKVF = (float*)(ws + 142606336);           // T x 4096 fp32
    unsigned short* QB   = (unsigned short*)(ws + 176160768);  // T x 2048
    unsigned short* KB   = (unsigned short*)(ws + 184549376);  // T x 1024
    unsigned short* VT   = (unsigned short*)(ws + 188743680);  // 1024 x T
    unsigned short* GATE = (unsigned short*)(ws + 142606336);  // T x 6144 (alias)
    unsigned short* ACT  = (unsigned short*)(ws + 167772160);  // T x 6144 (alias)

    auto cvt = [&](const float* s, unsigned short* dst, size_t n) {
        int n4 = (int)(n / 4);
        cvt_f32_bf16<<<dim3((n4 + 255) / 256), dim3(256), 0, stream>>>(s, dst, n4);
    };

    cvt(wq, WQKV,                 (size_t)kH  * kD * kHid);
    cvt(wk, WQKV + 2048 * kHid,   (size_t)kHK * kD * kHid);
    cvt(wv, WQKV + 3072 * kHid,   (size_t)kHK * kD * kHid);
    cvt(wo, WO,                   (size_t)kHid * kH * kD);
    cvt(wg, WG,                   (size_t)kFF * kHid);
    cvt(wu, WU,                   (size_t)kFF * kHid);
    cvt(wd, WD,                   (size_t)kHid * kFF);

    rmsnorm_k<<<dim3(kT), dim3(256), 0, stream>>>(hidden, ln1, XN1);

    // QKV GEMM: (T x 2048) x (4096 x 2048)^T -> fp32   [8-phase 256^2]
    gemm256<0><<<dim3(4096 / 256, kT / 256), dim3(512), 0, stream>>>(
        XN1, WQKV, QKVF, nullptr, nullptr, kT, 4096, kHid);

    qknorm_rope<<<dim3(kT, 6), dim3(256), 0, stream>>>(QKVF, positions, qnw, knw, QB, KB);

    vtrans<<<dim3(kT / 32, 1024 / 32), dim3(256), 0, stream>>>(QKVF, VT);

    attn_fwd2<<<dim3(kT / 32, kHK), dim3(256), 0, stream>>>(QB, KB, VT, OATT);

    gemm_bt<2><<<dim3(kHid / 128, kT / 128), dim3(256), 0, stream>>>(
        OATT, WO, H1, hidden, nullptr, kT, kHid, kHid);

    rmsnorm_k<<<dim3(kT), dim3(256), 0, stream>>>(H1, ln2, XN2);

    // gate GEMM -> bf16   [8-phase 256^2]
    gemm256<1><<<dim3(kFF / 256, kT / 256), dim3(512), 0, stream>>>(
        XN2, WG, GATE, nullptr, nullptr, kT, kFF, kHid);

    // up GEMM + fused silu(gate)*up -> bf16   [8-phase 256^2]
    gemm256<3><<<dim3(kFF / 256, kT / 256), dim3(512), 0, stream>>>(
        XN2, WU, ACT, nullptr, GATE, kT, kFF, kHid);

    // down GEMM + residual -> d_out fp32
    gemm_bt<2><<<dim3(kHid / 128, kT / 128), dim3(256), 0, stream>>>(
        ACT, WD, (float*)d_out, H1, nullptr, kT, kHid, kFF);
}

// Round 4
// 479.754 us; speedup vs baseline: 1.5150x; 1.1472x over previous
//
#include <hip/hip_runtime.h>
#include <hip/hip_bf16.h>
#include <stdint.h>

namespace {

constexpr int kT   = 2048;
constexpr int kHid = 2048;
constexpr int kH   = 16;
constexpr int kHK  = 8;
constexpr int kD   = 128;
constexpr int kFF  = 6144;

using bf16x8 = __attribute__((ext_vector_type(8))) short;
using f32x4  = __attribute__((ext_vector_type(4))) float;

__device__ __forceinline__ float bf2f(unsigned short u) {
    return __uint_as_float(((unsigned)u) << 16);
}
__device__ __forceinline__ unsigned short f2bf(float f) {
    unsigned u = __float_as_uint(f);
    return (unsigned short)((u + 0x7fffu + ((u >> 16) & 1u)) >> 16);
}
__device__ __forceinline__ void gload_lds16(const void* g, void* l) {
    __builtin_amdgcn_global_load_lds(
        (__attribute__((address_space(1))) void*)g,
        (__attribute__((address_space(3))) void*)l, 16, 0, 0);
}
__device__ __forceinline__ f32x4 mf(bf16x8 a, bf16x8 b, f32x4 c) {
    return __builtin_amdgcn_mfma_f32_16x16x32_bf16(a, b, c, 0, 0, 0);
}

// fp32 -> bf16 grid-stride convert (vectorized x4)
__global__ __launch_bounds__(256)
void cvt_f32_bf16(const float* __restrict__ src, unsigned short* __restrict__ dst, int n4) {
    int i = blockIdx.x * 256 + threadIdx.x;
    if (i < n4) {
        float4 v = ((const float4*)src)[i];
        ushort4 o;
        o.x = f2bf(v.x); o.y = f2bf(v.y); o.z = f2bf(v.z); o.w = f2bf(v.w);
        ((ushort4*)dst)[i] = o;
    }
}

// out = p0+p1+p2+p3+res (all fp32), vectorized x4
__global__ __launch_bounds__(256)
void reduce4(const float* __restrict__ p0, const float* __restrict__ p1,
             const float* __restrict__ p2, const float* __restrict__ p3,
             const float* __restrict__ res, float* __restrict__ out, int n4) {
    int i = blockIdx.x * 256 + threadIdx.x;
    if (i < n4) {
        float4 a = ((const float4*)p0)[i];
        float4 b = ((const float4*)p1)[i];
        float4 c = ((const float4*)p2)[i];
        float4 d = ((const float4*)p3)[i];
        float4 r = ((const float4*)res)[i];
        float4 o;
        o.x = a.x + b.x + c.x + d.x + r.x;
        o.y = a.y + b.y + c.y + d.y + r.y;
        o.z = a.z + b.z + c.z + d.z + r.z;
        o.w = a.w + b.w + c.w + d.w + r.w;
        ((float4*)out)[i] = o;
    }
}

// RMSNorm over HID=2048, fp32 in -> bf16 out. 1 block per row.
__global__ __launch_bounds__(256)
void rmsnorm_k(const float* __restrict__ x, const float* __restrict__ w,
               unsigned short* __restrict__ out) {
    const int row = blockIdx.x;
    const int tid = threadIdx.x;
    const float4* xr = (const float4*)(x + (size_t)row * kHid);
    float4 v0 = xr[tid];
    float4 v1 = xr[tid + 256];
    float ss = v0.x*v0.x + v0.y*v0.y + v0.z*v0.z + v0.w*v0.w
             + v1.x*v1.x + v1.y*v1.y + v1.z*v1.z + v1.w*v1.w;
#pragma unroll
    for (int m = 1; m < 64; m <<= 1) ss += __shfl_xor(ss, m);
    __shared__ float red[4];
    if ((tid & 63) == 0) red[tid >> 6] = ss;
    __syncthreads();
    float tot = red[0] + red[1] + red[2] + red[3];
    float rs = rsqrtf(tot * (1.0f / kHid) + 1e-6f);
    const float4* wv = (const float4*)w;
    float4 w0 = wv[tid], w1 = wv[tid + 256];
    ushort4 o0, o1;
    o0.x = f2bf(v0.x * rs * w0.x); o0.y = f2bf(v0.y * rs * w0.y);
    o0.z = f2bf(v0.z * rs * w0.z); o0.w = f2bf(v0.w * rs * w0.w);
    o1.x = f2bf(v1.x * rs * w1.x); o1.y = f2bf(v1.y * rs * w1.y);
    o1.z = f2bf(v1.z * rs * w1.z); o1.w = f2bf(v1.w * rs * w1.w);
    ushort4* orow = (ushort4*)(out + (size_t)row * kHid);
    orow[tid] = o0;
    orow[tid + 256] = o1;
}

// -------- 256x256 8-phase GEMM (T2+T3+T4+T5 template) --------
// 512 threads = 8 waves (2M x 4N), BK=64, 2 K-tiles per iteration.
// LDS 128 KiB: smem[buf][region][128*64], region 0/1 = A half 0/1 (rows),
// region 2/3 = B half 0/1. Counted vmcnt(6), never drained in main loop.
// EPI: 0 = fp32 store, 1 = bf16 store, 2 = fp32 + Res, 3 = silu(G)*acc bf16,
//      4 = split-K fp32 partial store to p[blockIdx.z], K-range = z*KS..+KS.
template <int EPI>
__global__ __launch_bounds__(512, 2)
void gemm256(const unsigned short* __restrict__ A,
             const unsigned short* __restrict__ B,
             void* __restrict__ C,
             const float* __restrict__ Res,
             const unsigned short* __restrict__ G,
             int M, int N, int K, int KS,
             float* __restrict__ p0, float* __restrict__ p1,
             float* __restrict__ p2, float* __restrict__ p3) {
    __shared__ unsigned short smem[2][4][128 * 64];  // 128 KiB

    const int tid  = threadIdx.x;
    const int lane = tid & 63;
    const int l15  = lane & 15;
    const int g4   = lane >> 4;
    const int wid  = tid >> 6;   // 0..7
    const int wr   = wid >> 2;   // 0..1  (M half)
    const int wc   = wid & 3;    // 0..3  (N quarter)
    const int bm   = blockIdx.y * 256;
    const int bn   = blockIdx.x * 256;
    const int kb   = (EPI == 4) ? blockIdx.z * KS : 0;
    const int NT   = ((EPI == 4) ? KS : K) >> 6;
    const int NI   = NT >> 1;

    f32x4 acc[8][4] = {};

    // stage one 16KB half-tile (2 gload_lds x 512 threads).
    // linear LDS dest + inverse-swizzled global source (guide rule 21).
    auto stage = [&](int b, int reg, int t) {
        const unsigned short* Base = (reg < 2) ? A : B;
        const int br = ((reg < 2) ? bm : bn) + (reg & 1) * 128;
#pragma unroll
        for (int i = 0; i < 2; ++i) {
            int ch   = tid + i * 512;
            int row  = ch >> 3;
            int slot = (ch & 7) ^ (row & 7);
            gload_lds16(Base + (size_t)(br + row) * K + kb + t * 64 + slot * 8,
                        (char*)&smem[b][reg][0] + ch * 16);
        }
    };
    auto rdA = [&](int b, int m, int ks) {
        int row = m * 16 + l15;
        return *(const bf16x8*)((const char*)&smem[b][wr][0]
               + row * 128 + (((ks * 4 + g4) ^ (row & 7)) * 16));
    };
    auto rdB = [&](int b, int n, int ks) {
        int row = wc * 64 + n * 16 + l15;   // 0..255 within N-tile
        return *(const bf16x8*)((const char*)&smem[b][2 + (row >> 7)][0]
               + (row & 127) * 128 + (((ks * 4 + g4) ^ (row & 7)) * 16));
    };

    // prologue: tile0 {Bh0,Bh1,Ah0,Ah1} -> buf0; tile1 {Bh0,Bh1,Ah0} -> buf1 (14 loads)
    stage(0, 2, 0); stage(0, 3, 0); stage(0, 0, 0); stage(0, 1, 0);
    stage(1, 2, 1); stage(1, 3, 1); stage(1, 0, 1);
    asm volatile("s_waitcnt vmcnt(6)" ::: "memory");
    __builtin_amdgcn_s_barrier();

    for (int i = 0; i < NI; ++i) {
        const int e  = 2 * i;
        const int o  = e + 1;
        const bool pf = (e + 2 < NT);
        bf16x8 af[4][2], bfr[4][2];

        // ---- P1: read all B + A(m0-3) of tile e (buf0); stage Ah1(o)->buf1 ----
#pragma unroll
        for (int m = 0; m < 4; ++m) { af[m][0] = rdA(0, m, 0); af[m][1] = rdA(0, m, 1); }
#pragma unroll
        for (int n = 0; n < 4; ++n) { bfr[n][0] = rdB(0, n, 0); bfr[n][1] = rdB(0, n, 1); }
        stage(1, 1, o);
        __builtin_amdgcn_s_barrier();
        asm volatile("s_waitcnt lgkmcnt(0)" ::: "memory");
        __builtin_amdgcn_sched_barrier(0);
        __builtin_amdgcn_s_setprio(1);
#pragma unroll
        for (int m = 0; m < 4; ++m)
#pragma unroll
            for (int n = 0; n < 2; ++n) {
                acc[m][n] = mf(af[m][0], bfr[n][0], acc[m][n]);
                acc[m][n] = mf(af[m][1], bfr[n][1], acc[m][n]);
            }
        __builtin_amdgcn_s_setprio(0);
        __builtin_amdgcn_s_barrier();

        // ---- P2: stage Bh0(e+2)->buf0; MFMA m0-3 x n2-3 ----
        if (pf) stage(0, 2, e + 2);
        __builtin_amdgcn_s_barrier();
        __builtin_amdgcn_s_setprio(1);
#pragma unroll
        for (int m = 0; m < 4; ++m)
#pragma unroll
            for (int n = 2; n < 4; ++n) {
                acc[m][n] = mf(af[m][0], bfr[n][0], acc[m][n]);
                acc[m][n] = mf(af[m][1], bfr[n][1], acc[m][n]);
            }
        __builtin_amdgcn_s_setprio(0);
        __builtin_amdgcn_s_barrier();

        // ---- P3: read A(m4-7) tile e; stage Bh1(e+2)->buf0; MFMA m4-7 x n0-1 ----
#pragma unroll
        for (int m = 0; m < 4; ++m) { af[m][0] = rdA(0, 4 + m, 0); af[m][1] = rdA(0, 4 + m, 1); }
        if (pf) stage(0, 3, e + 2);
        __builtin_amdgcn_s_barrier();
        asm volatile("s_waitcnt lgkmcnt(0)" ::: "memory");
        __builtin_amdgcn_sched_barrier(0);
        __builtin_amdgcn_s_setprio(1);
#pragma unroll
        for (int m = 0; m < 4; ++m)
#pragma unroll
            for (int n = 0; n < 2; ++n) {
                acc[4 + m][n] = mf(af[m][0], bfr[n][0], acc[4 + m][n]);
                acc[4 + m][n] = mf(af[m][1], bfr[n][1], acc[4 + m][n]);
            }
        __builtin_amdgcn_s_setprio(0);
        __builtin_amdgcn_s_barrier();

        // ---- P4: stage Ah0(e+2)->buf0; MFMA m4-7 x n2-3; vmcnt gate for tile o ----
        if (pf) stage(0, 0, e + 2);
        __builtin_amdgcn_s_barrier();
        __builtin_amdgcn_s_setprio(1);
#pragma unroll
        for (int m = 0; m < 4; ++m)
#pragma unroll
            for (int n = 2; n < 4; ++n) {
                acc[4 + m][n] = mf(af[m][0], bfr[n][0], acc[4 + m][n]);
                acc[4 + m][n] = mf(af[m][1], bfr[n][1], acc[4 + m][n]);
            }
        __builtin_amdgcn_s_setprio(0);
        if (pf) asm volatile("s_waitcnt vmcnt(6)" ::: "memory");
        else    asm volatile("s_waitcnt vmcnt(0)" ::: "memory");
        __builtin_amdgcn_s_barrier();

        // ---- P5: read all B + A(m0-3) of tile o (buf1); stage Ah1(e+2)->buf0 ----
#pragma unroll
        for (int m = 0; m < 4; ++m) { af[m][0] = rdA(1, m, 0); af[m][1] = rdA(1, m, 1); }
#pragma unroll
        for (int n = 0; n < 4; ++n) { bfr[n][0] = rdB(1, n, 0); bfr[n][1] = rdB(1, n, 1); }
        if (pf) stage(0, 1, e + 2);
        __builtin_amdgcn_s_barrier();
        asm volatile("s_waitcnt lgkmcnt(0)" ::: "memory");
        __builtin_amdgcn_sched_barrier(0);
        __builtin_amdgcn_s_setprio(1);
#pragma unroll
        for (int m = 0; m < 4; ++m)
#pragma unroll
            for (int n = 0; n < 2; ++n) {
                acc[m][n] = mf(af[m][0], bfr[n][0], acc[m][n]);
                acc[m][n] = mf(af[m][1], bfr[n][1], acc[m][n]);
            }
        __builtin_amdgcn_s_setprio(0);
        __builtin_amdgcn_s_barrier();

        // ---- P6: stage Bh0(o+2)->buf1; MFMA m0-3 x n2-3 ----
        if (pf) stage(1, 2, o + 2);
        __builtin_amdgcn_s_barrier();
        __builtin_amdgcn_s_setprio(1);
#pragma unroll
        for (int m = 0; m < 4; ++m)
#pragma unroll
            for (int n = 2; n < 4; ++n) {
                acc[m][n] = mf(af[m][0], bfr[n][0], acc[m][n]);
                acc[m][n] = mf(af[m][1], bfr[n][1], acc[m][n]);
            }
        __builtin_amdgcn_s_setprio(0);
        __builtin_amdgcn_s_barrier();

        // ---- P7: read A(m4-7) tile o; stage Bh1(o+2)->buf1; MFMA m4-7 x n0-1 ----
#pragma unroll
        for (int m = 0; m < 4; ++m) { af[m][0] = rdA(1, 4 + m, 0); af[m][1] = rdA(1, 4 + m, 1); }
        if (pf) stage(1, 3, o + 2);
        __builtin_amdgcn_s_barrier();
        asm volatile("s_waitcnt lgkmcnt(0)" ::: "memory");
        __builtin_amdgcn_sched_barrier(0);
        __builtin_amdgcn_s_setprio(1);
#pragma unroll
        for (int m = 0; m < 4; ++m)
#pragma unroll
            for (int n = 0; n < 2; ++n) {
                acc[4 + m][n] = mf(af[m][0], bfr[n][0], acc[4 + m][n]);
                acc[4 + m][n] = mf(af[m][1], bfr[n][1], acc[4 + m][n]);
            }
        __builtin_amdgcn_s_setprio(0);
        __builtin_amdgcn_s_barrier();

        // ---- P8: stage Ah0(o+2)->buf1; MFMA m4-7 x n2-3; vmcnt gate for tile e+2 ----
        if (pf) stage(1, 0, o + 2);
        __builtin_amdgcn_s_barrier();
        __builtin_amdgcn_s_setprio(1);
#pragma unroll
        for (int m = 0; m < 4; ++m)
#pragma unroll
            for (int n = 2; n < 4; ++n) {
                acc[4 + m][n] = mf(af[m][0], bfr[n][0], acc[4 + m][n]);
                acc[4 + m][n] = mf(af[m][1], bfr[n][1], acc[4 + m][n]);
            }
        __builtin_amdgcn_s_setprio(0);
        if (pf) asm volatile("s_waitcnt vmcnt(6)" ::: "memory");
        __builtin_amdgcn_s_barrier();
    }

    // epilogue
    float* P = nullptr;
    if (EPI == 4) {
        const int z = blockIdx.z;
        P = (z == 0) ? p0 : (z == 1) ? p1 : (z == 2) ? p2 : p3;
    }
#pragma unroll
    for (int m = 0; m < 8; ++m) {
#pragma unroll
        for (int n = 0; n < 4; ++n) {
            int row = bm + wr * 128 + m * 16 + g4 * 4;
            int col = bn + wc * 64 + n * 16 + l15;
#pragma unroll
            for (int r = 0; r < 4; ++r) {
                size_t idx = (size_t)(row + r) * N + col;
                float v = acc[m][n][r];
                if (EPI == 0) {
                    ((float*)C)[idx] = v;
                } else if (EPI == 1) {
                    ((unsigned short*)C)[idx] = f2bf(v);
                } else if (EPI == 2) {
                    ((float*)C)[idx] = v + Res[idx];
                } else if (EPI == 3) {
                    float g = bf2f(G[idx]);
                    ((unsigned short*)C)[idx] = f2bf(g / (1.0f + __expf(-g)) * v);
                } else {
                    P[idx] = v;
                }
            }
        }
    }
}

// Fused per-head RMSNorm (D=128) + RoPE for q and k.
__global__ __launch_bounds__(256)
void qknorm_rope(const float* __restrict__ qkv, const int* __restrict__ positions,
                 const float* __restrict__ qnw, const float* __restrict__ knw,
                 unsigned short* __restrict__ Qo, unsigned short* __restrict__ Ko) {
    const int t    = blockIdx.x;
    const int j    = blockIdx.y * 4 + (threadIdx.x >> 6);  // 0..23
    const int lane = threadIdx.x & 63;
    const float* src = qkv + (size_t)t * 4096 + j * 128;
    float x1 = src[lane];
    float x2 = src[lane + 64];
    float ss = x1 * x1 + x2 * x2;
#pragma unroll
    for (int m = 1; m < 64; m <<= 1) ss += __shfl_xor(ss, m);
    float rs = rsqrtf(ss * (1.0f / 128.0f) + 1e-6f);
    const float* w = (j < 16) ? qnw : knw;
    float n1 = x1 * rs * w[lane];
    float n2 = x2 * rs * w[lane + 64];
    float inv = powf(1.0e6f, -(float)lane * (1.0f / 64.0f));
    float fr = (float)positions[t] * inv;
    float sn, cs;
    sincosf(fr, &sn, &cs);
    float o1 = n1 * cs - n2 * sn;
    float o2 = n2 * cs + n1 * sn;
    if (j < 16) {
        unsigned short* d = Qo + (size_t)t * (kH * kD) + j * kD;
        d[lane] = f2bf(o1);
        d[lane + 64] = f2bf(o2);
    } else {
        unsigned short* d = Ko + (size_t)t * (kHK * kD) + (j - 16) * kD;
        d[lane] = f2bf(o1);
        d[lane + 64] = f2bf(o2);
    }
}

// V transpose: qkv fp32 v-part -> Vt bf16 (1024 x T)
__global__ __launch_bounds__(256)
void vtrans(const float* __restrict__ qkv, unsigned short* __restrict__ Vt) {
    __shared__ float tile[32][33];
    const int t0 = blockIdx.x * 32;
    const int d0 = blockIdx.y * 32;
    const int tc = threadIdx.x & 31;
    const int tr = threadIdx.x >> 5;  // 0..7
#pragma unroll
    for (int i = 0; i < 4; ++i) {
        int trow = tr + i * 8;
        tile[trow][tc] = qkv[(size_t)(t0 + trow) * 4096 + 3072 + d0 + tc];
    }
    __syncthreads();
#pragma unroll
    for (int i = 0; i < 4; ++i) {
        int drow = tr + i * 8;
        Vt[(size_t)(d0 + drow) * kT + t0 + tc] = f2bf(tile[tc][drow]);
    }
}

// Causal flash attention: 4 waves/block share one kv-head, KVBLK=64,
// K/V staged in LDS (double-buffered, global_load_lds, XOR-swizzled).
__global__ __launch_bounds__(256)
void attn_fwd2(const unsigned short* __restrict__ Q,   // T x (H*D)
               const unsigned short* __restrict__ Kc,  // T x (HK*D)
               const unsigned short* __restrict__ Vt,  // (HK*D) x T
               unsigned short* __restrict__ O) {       // T x (H*D)
    __shared__ unsigned short Ks[2][64 * 128];
    __shared__ unsigned short Vs[2][128 * 64];
    __shared__ unsigned short P_lds[4][16 * 72];

    const int tid  = threadIdx.x;
    const int lane = tid & 63;
    const int l15  = lane & 15;
    const int g4   = lane >> 4;
    const int wid  = tid >> 6;
    const int hkk  = blockIdx.y;
    const int h    = hkk * 2 + (wid >> 1);
    const int q0   = blockIdx.x * 32 + (wid & 1) * 16;
    const int nch  = blockIdx.x / 2 + 1;

    bf16x8 qf[4];
#pragma unroll
    for (int ks = 0; ks < 4; ++ks)
        qf[ks] = *(const bf16x8*)(Q + (size_t)(q0 + l15) * (kH * kD) + h * kD + ks * 32 + g4 * 8);

    f32x4 oacc[8] = {};
    float mrow[4] = {-3e38f, -3e38f, -3e38f, -3e38f};
    float lrow[4] = {0.f, 0.f, 0.f, 0.f};
    const float scale = 0.08838834764831845f;  // 1/sqrt(128)

    auto stage = [&](int b, int kv0) {
#pragma unroll
        for (int i = 0; i < 4; ++i) {
            int ch  = tid + i * 256;
            int row = ch >> 4;
            int c16 = ch & 15;
            gload_lds16(Kc + (size_t)(kv0 + row) * (kHK * kD) + hkk * kD
                            + ((c16 ^ (row & 7)) * 8),
                        (char*)Ks[b] + ch * 16);
        }
#pragma unroll
        for (int i = 0; i < 4; ++i) {
            int ch  = tid + i * 256;
            int row = ch >> 3;
            int c8  = ch & 7;
            gload_lds16(Vt + (size_t)(hkk * kD + row) * kT + kv0
                            + ((c8 ^ (row & 7)) * 8),
                        (char*)Vs[b] + ch * 16);
        }
    };

    stage(0, 0);
    __syncthreads();

    for (int c = 0; c < nch; ++c) {
        const int kv0 = c * 64;
        const int b   = c & 1;
        if (c + 1 < nch) stage(b ^ 1, kv0 + 64);

        if (kv0 <= q0 + 15) {
            f32x4 s[4] = {};
#pragma unroll
            for (int half = 0; half < 4; ++half) {
                const int row = half * 16 + l15;
#pragma unroll
                for (int ks = 0; ks < 4; ++ks) {
                    bf16x8 kf = *(const bf16x8*)((const char*)Ks[b]
                                  + row * 256 + (((ks * 4 + g4) ^ (row & 7)) * 16));
                    s[half] = mf(qf[ks], kf, s[half]);
                }
            }
            float pv[4][4];
#pragma unroll
            for (int half = 0; half < 4; ++half)
#pragma unroll
                for (int r = 0; r < 4; ++r) {
                    float v = s[half][r] * scale;
                    int qi = q0 + g4 * 4 + r;
                    int ki = kv0 + half * 16 + l15;
                    pv[half][r] = (ki > qi) ? -3e38f : v;
                }
#pragma unroll
            for (int r = 0; r < 4; ++r) {
                float rm = fmaxf(fmaxf(pv[0][r], pv[1][r]), fmaxf(pv[2][r], pv[3][r]));
#pragma unroll
                for (int msk = 1; msk < 16; msk <<= 1)
                    rm = fmaxf(rm, __shfl_xor(rm, msk));
                float mnew = fmaxf(mrow[r], rm);
                float corr = __expf(mrow[r] - mnew);
                mrow[r] = mnew;
                lrow[r] *= corr;
#pragma unroll
                for (int c2 = 0; c2 < 8; ++c2)
                    oacc[c2][r] *= corr;
                float ps = 0.f;
#pragma unroll
                for (int half = 0; half < 4; ++half) {
                    float p = __expf(pv[half][r] - mnew);
                    ps += p;
                    P_lds[wid][(g4 * 4 + r) * 72 + half * 16 + l15] = f2bf(p);
                }
#pragma unroll
                for (int msk = 1; msk < 16; msk <<= 1)
                    ps += __shfl_xor(ps, msk);
                lrow[r] += ps;
            }
            asm volatile("s_waitcnt lgkmcnt(0)" ::: "memory");
            __builtin_amdgcn_sched_barrier(0);
            bf16x8 pa[2];
#pragma unroll
            for (int ks2 = 0; ks2 < 2; ++ks2)
                pa[ks2] = *(const bf16x8*)(&P_lds[wid][l15 * 72 + ks2 * 32 + g4 * 8]);
#pragma unroll
            for (int c2 = 0; c2 < 8; ++c2) {
                const int d = c2 * 16 + l15;
#pragma unroll
                for (int ks2 = 0; ks2 < 2; ++ks2) {
                    bf16x8 vf = *(const bf16x8*)((const char*)Vs[b]
                                  + d * 128 + (((ks2 * 4 + g4) ^ (d & 7)) * 16));
                    oacc[c2] = mf(pa[ks2], vf, oacc[c2]);
                }
            }
        }
        __syncthreads();
    }

#pragma unroll
    for (int c2 = 0; c2 < 8; ++c2)
#pragma unroll
        for (int r = 0; r < 4; ++r) {
            float v = oacc[c2][r] / lrow[r];
            O[(size_t)(q0 + g4 * 4 + r) * (kH * kD) + h * kD + c2 * 16 + l15] = f2bf(v);
        }
}

}  // namespace

extern "C" void kernel_launch(void* const* d_in, const int* in_sizes, int n_in,
                              void* d_out, int out_size, void* d_ws, size_t ws_size,
                              hipStream_t stream) {
    (void)in_sizes; (void)n_in; (void)out_size; (void)ws_size;

    const int*   positions = (const int*)  d_in[0];
    const float* hidden    = (const float*)d_in[1];
    const float* wq  = (const float*)d_in[2];
    const float* wk  = (const float*)d_in[3];
    const float* wv  = (const float*)d_in[4];
    const float* wo  = (const float*)d_in[5];
    const float* qnw = (const float*)d_in[6];
    const float* knw = (const float*)d_in[7];
    const float* ln1 = (const float*)d_in[8];
    const float* ln2 = (const float*)d_in[9];
    const float* wg  = (const float*)d_in[10];
    const float* wu  = (const float*)d_in[11];
    const float* wd  = (const float*)d_in[12];

    char* ws = (char*)d_ws;
    unsigned short* WQKV = (unsigned short*)(ws + 0);          // 4096x2048 bf16
    unsigned short* WO   = (unsigned short*)(ws + 16777216);   // 2048x2048
    unsigned short* WG   = (unsigned short*)(ws + 25165824);   // 6144x2048
    unsigned short* WU   = (unsigned short*)(ws + 50331648);   // 6144x2048
    unsigned short* WD   = (unsigned short*)(ws + 75497472);   // 2048x6144
    unsigned short* XN1  = (unsigned short*)(ws + 100663296);  // T x 2048
    unsigned short* OATT = (unsigned short*)(ws + 109051904);  // T x 2048
    float*          H1   = (float*)(ws + 117440512);           // T x 2048 fp32
    unsigned short* XN2  = (unsigned short*)(ws + 134217728);  // T x 2048
    float*          QKVF = (float*)(ws + 142606336);           // T x 4096 fp32
    unsigned short* QB   = (unsigned short*)(ws + 176160768);  // T x 2048
    unsigned short* KB   = (unsigned short*)(ws + 184549376);  // T x 1024
    unsigned short* VT   = (unsigned short*)(ws + 188743680);  // 1024 x T
    unsigned short* GATE = (unsigned short*)(ws + 142606336);  // T x 6144 (alias QKVF)
    unsigned short* ACT  = (unsigned short*)(ws + 167772160);  // T x 6144 (alias)

    // O-proj split-K partials (dead regions at that point: QKVF.., QB/KB/VT, WQKV)
    float* OP0 = (float*)(ws + 142606336);
    float* OP1 = (float*)(ws + 159383552);
    float* OP2 = (float*)(ws + 176160768);
    float* OP3 = (float*)(ws + 0);
    // down-proj split-K partials (dead: WQKV/WO/WG prefix, GATE region)
    float* DP0 = (float*)(ws + 0);
    float* DP1 = (float*)(ws + 16777216);
    float* DP2 = (float*)(ws + 33554432);
    float* DP3 = (float*)(ws + 142606336);

    auto cvt = [&](const float* s, unsigned short* dst, size_t n) {
        int n4 = (int)(n / 4);
        cvt_f32_bf16<<<dim3((n4 + 255) / 256), dim3(256), 0, stream>>>(s, dst, n4);
    };

    cvt(wq, WQKV,                 (size_t)kH  * kD * kHid);
    cvt(wk, WQKV + 2048 * kHid,   (size_t)kHK * kD * kHid);
    cvt(wv, WQKV + 3072 * kHid,   (size_t)kHK * kD * kHid);
    cvt(wo, WO,                   (size_t)kHid * kH * kD);
    cvt(wg, WG,                   (size_t)kFF * kHid);
    cvt(wu, WU,                   (size_t)kFF * kHid);
    cvt(wd, WD,                   (size_t)kHid * kFF);

    rmsnorm_k<<<dim3(kT), dim3(256), 0, stream>>>(hidden, ln1, XN1);

    // QKV GEMM: (T x 2048) x (4096 x 2048)^T -> fp32   [8-phase 256^2]
    gemm256<0><<<dim3(4096 / 256, kT / 256), dim3(512), 0, stream>>>(
        XN1, WQKV, QKVF, nullptr, nullptr, kT, 4096, kHid, kHid,
        nullptr, nullptr, nullptr, nullptr);

    qknorm_rope<<<dim3(kT, 6), dim3(256), 0, stream>>>(QKVF, positions, qnw, knw, QB, KB);

    vtrans<<<dim3(kT / 32, 1024 / 32), dim3(256), 0, stream>>>(QKVF, VT);

    attn_fwd2<<<dim3(kT / 32, kHK), dim3(256), 0, stream>>>(QB, KB, VT, OATT);

    // O-proj GEMM split-K=4 (KS=512, NT=8) -> partials, then reduce + residual
    gemm256<4><<<dim3(kHid / 256, kT / 256, 4), dim3(512), 0, stream>>>(
        OATT, WO, nullptr, nullptr, nullptr, kT, kHid, kHid, 512,
        OP0, OP1, OP2, OP3);
    reduce4<<<dim3(kT * kHid / 4 / 256), dim3(256), 0, stream>>>(
        OP0, OP1, OP2, OP3, hidden, H1, kT * kHid / 4);

    rmsnorm_k<<<dim3(kT), dim3(256), 0, stream>>>(H1, ln2, XN2);

    // gate GEMM -> bf16   [8-phase 256^2]
    gemm256<1><<<dim3(kFF / 256, kT / 256), dim3(512), 0, stream>>>(
        XN2, WG, GATE, nullptr, nullptr, kT, kFF, kHid, kHid,
        nullptr, nullptr, nullptr, nullptr);

    // up GEMM + fused silu(gate)*up -> bf16   [8-phase 256^2]
    gemm256<3><<<dim3(kFF / 256, kT / 256), dim3(512), 0, stream>>>(
        XN2, WU, ACT, nullptr, GATE, kT, kFF, kHid, kHid,
        nullptr, nullptr, nullptr, nullptr);

    // down GEMM split-K=4 (KS=1536, NT=24) -> partials, then reduce + residual
    gemm256<4><<<dim3(kHid / 256, kT / 256, 4), dim3(512), 0, stream>>>(
        ACT, WD, nullptr, nullptr, nullptr, kT, kHid, kFF, 1536,
        DP0, DP1, DP2, DP3);
    reduce4<<<dim3(kT * kHid / 4 / 256), dim3(256), 0, stream>>>(
        DP0, DP1, DP2, DP3, H1, (float*)d_out, kT * kHid / 4);
}

// Round 5
// 459.943 us; speedup vs baseline: 1.5803x; 1.0431x over previous
//
#include <hip/hip_runtime.h>
#include <hip/hip_bf16.h>
#include <stdint.h>

namespace {

constexpr int kT   = 2048;
constexpr int kHid = 2048;
constexpr int kH   = 16;
constexpr int kHK  = 8;
constexpr int kD   = 128;
constexpr int kFF  = 6144;

using bf16x8 = __attribute__((ext_vector_type(8))) short;
using f32x4  = __attribute__((ext_vector_type(4))) float;

__device__ __forceinline__ float bf2f(unsigned short u) {
    return __uint_as_float(((unsigned)u) << 16);
}
__device__ __forceinline__ unsigned short f2bf(float f) {
    unsigned u = __float_as_uint(f);
    return (unsigned short)((u + 0x7fffu + ((u >> 16) & 1u)) >> 16);
}
__device__ __forceinline__ void gload_lds16(const void* g, void* l) {
    __builtin_amdgcn_global_load_lds(
        (__attribute__((address_space(1))) void*)g,
        (__attribute__((address_space(3))) void*)l, 16, 0, 0);
}
__device__ __forceinline__ f32x4 mf(bf16x8 a, bf16x8 b, f32x4 c) {
    return __builtin_amdgcn_mfma_f32_16x16x32_bf16(a, b, c, 0, 0, 0);
}

// fp32 -> bf16 grid-stride convert (vectorized x4)
__global__ __launch_bounds__(256)
void cvt_f32_bf16(const float* __restrict__ src, unsigned short* __restrict__ dst, int n4) {
    int i = blockIdx.x * 256 + threadIdx.x;
    if (i < n4) {
        float4 v = ((const float4*)src)[i];
        ushort4 o;
        o.x = f2bf(v.x); o.y = f2bf(v.y); o.z = f2bf(v.z); o.w = f2bf(v.w);
        ((ushort4*)dst)[i] = o;
    }
}

// out = p0+p1+p2+p3+res (all fp32), vectorized x4
__global__ __launch_bounds__(256)
void reduce4(const float* __restrict__ p0, const float* __restrict__ p1,
             const float* __restrict__ p2, const float* __restrict__ p3,
             const float* __restrict__ res, float* __restrict__ out, int n4) {
    int i = blockIdx.x * 256 + threadIdx.x;
    if (i < n4) {
        float4 a = ((const float4*)p0)[i];
        float4 b = ((const float4*)p1)[i];
        float4 c = ((const float4*)p2)[i];
        float4 d = ((const float4*)p3)[i];
        float4 r = ((const float4*)res)[i];
        float4 o;
        o.x = a.x + b.x + c.x + d.x + r.x;
        o.y = a.y + b.y + c.y + d.y + r.y;
        o.z = a.z + b.z + c.z + d.z + r.z;
        o.w = a.w + b.w + c.w + d.w + r.w;
        ((float4*)out)[i] = o;
    }
}

// RMSNorm over HID=2048, fp32 in -> bf16 out. 1 block per row.
__global__ __launch_bounds__(256)
void rmsnorm_k(const float* __restrict__ x, const float* __restrict__ w,
               unsigned short* __restrict__ out) {
    const int row = blockIdx.x;
    const int tid = threadIdx.x;
    const float4* xr = (const float4*)(x + (size_t)row * kHid);
    float4 v0 = xr[tid];
    float4 v1 = xr[tid + 256];
    float ss = v0.x*v0.x + v0.y*v0.y + v0.z*v0.z + v0.w*v0.w
             + v1.x*v1.x + v1.y*v1.y + v1.z*v1.z + v1.w*v1.w;
#pragma unroll
    for (int m = 1; m < 64; m <<= 1) ss += __shfl_xor(ss, m);
    __shared__ float red[4];
    if ((tid & 63) == 0) red[tid >> 6] = ss;
    __syncthreads();
    float tot = red[0] + red[1] + red[2] + red[3];
    float rs = rsqrtf(tot * (1.0f / kHid) + 1e-6f);
    const float4* wv = (const float4*)w;
    float4 w0 = wv[tid], w1 = wv[tid + 256];
    ushort4 o0, o1;
    o0.x = f2bf(v0.x * rs * w0.x); o0.y = f2bf(v0.y * rs * w0.y);
    o0.z = f2bf(v0.z * rs * w0.z); o0.w = f2bf(v0.w * rs * w0.w);
    o1.x = f2bf(v1.x * rs * w1.x); o1.y = f2bf(v1.y * rs * w1.y);
    o1.z = f2bf(v1.z * rs * w1.z); o1.w = f2bf(v1.w * rs * w1.w);
    ushort4* orow = (ushort4*)(out + (size_t)row * kHid);
    orow[tid] = o0;
    orow[tid + 256] = o1;
}

// -------- 256x256 8-phase GEMM (T2+T3+T4+T5 template) --------
// EPI: 0 = fp32 store, 1 = bf16 store, 2 = fp32 + Res, 3 = silu(G)*acc bf16,
//      4 = split-K fp32 partial store to p[blockIdx.z], K-range = z*KS..+KS.
template <int EPI>
__global__ __launch_bounds__(512, 2)
void gemm256(const unsigned short* __restrict__ A,
             const unsigned short* __restrict__ B,
             void* __restrict__ C,
             const float* __restrict__ Res,
             const unsigned short* __restrict__ G,
             int M, int N, int K, int KS,
             float* __restrict__ p0, float* __restrict__ p1,
             float* __restrict__ p2, float* __restrict__ p3) {
    __shared__ unsigned short smem[2][4][128 * 64];  // 128 KiB

    const int tid  = threadIdx.x;
    const int lane = tid & 63;
    const int l15  = lane & 15;
    const int g4   = lane >> 4;
    const int wid  = tid >> 6;   // 0..7
    const int wr   = wid >> 2;   // 0..1  (M half)
    const int wc   = wid & 3;    // 0..3  (N quarter)
    const int bm   = blockIdx.y * 256;
    const int bn   = blockIdx.x * 256;
    const int kb   = (EPI == 4) ? blockIdx.z * KS : 0;
    const int NT   = ((EPI == 4) ? KS : K) >> 6;
    const int NI   = NT >> 1;

    f32x4 acc[8][4] = {};

    auto stage = [&](int b, int reg, int t) {
        const unsigned short* Base = (reg < 2) ? A : B;
        const int br = ((reg < 2) ? bm : bn) + (reg & 1) * 128;
#pragma unroll
        for (int i = 0; i < 2; ++i) {
            int ch   = tid + i * 512;
            int row  = ch >> 3;
            int slot = (ch & 7) ^ (row & 7);
            gload_lds16(Base + (size_t)(br + row) * K + kb + t * 64 + slot * 8,
                        (char*)&smem[b][reg][0] + ch * 16);
        }
    };
    auto rdA = [&](int b, int m, int ks) {
        int row = m * 16 + l15;
        return *(const bf16x8*)((const char*)&smem[b][wr][0]
               + row * 128 + (((ks * 4 + g4) ^ (row & 7)) * 16));
    };
    auto rdB = [&](int b, int n, int ks) {
        int row = wc * 64 + n * 16 + l15;
        return *(const bf16x8*)((const char*)&smem[b][2 + (row >> 7)][0]
               + (row & 127) * 128 + (((ks * 4 + g4) ^ (row & 7)) * 16));
    };

    stage(0, 2, 0); stage(0, 3, 0); stage(0, 0, 0); stage(0, 1, 0);
    stage(1, 2, 1); stage(1, 3, 1); stage(1, 0, 1);
    asm volatile("s_waitcnt vmcnt(6)" ::: "memory");
    __builtin_amdgcn_s_barrier();

    for (int i = 0; i < NI; ++i) {
        const int e  = 2 * i;
        const int o  = e + 1;
        const bool pf = (e + 2 < NT);
        bf16x8 af[4][2], bfr[4][2];

#pragma unroll
        for (int m = 0; m < 4; ++m) { af[m][0] = rdA(0, m, 0); af[m][1] = rdA(0, m, 1); }
#pragma unroll
        for (int n = 0; n < 4; ++n) { bfr[n][0] = rdB(0, n, 0); bfr[n][1] = rdB(0, n, 1); }
        stage(1, 1, o);
        __builtin_amdgcn_s_barrier();
        asm volatile("s_waitcnt lgkmcnt(0)" ::: "memory");
        __builtin_amdgcn_sched_barrier(0);
        __builtin_amdgcn_s_setprio(1);
#pragma unroll
        for (int m = 0; m < 4; ++m)
#pragma unroll
            for (int n = 0; n < 2; ++n) {
                acc[m][n] = mf(af[m][0], bfr[n][0], acc[m][n]);
                acc[m][n] = mf(af[m][1], bfr[n][1], acc[m][n]);
            }
        __builtin_amdgcn_s_setprio(0);
        __builtin_amdgcn_s_barrier();

        if (pf) stage(0, 2, e + 2);
        __builtin_amdgcn_s_barrier();
        __builtin_amdgcn_s_setprio(1);
#pragma unroll
        for (int m = 0; m < 4; ++m)
#pragma unroll
            for (int n = 2; n < 4; ++n) {
                acc[m][n] = mf(af[m][0], bfr[n][0], acc[m][n]);
                acc[m][n] = mf(af[m][1], bfr[n][1], acc[m][n]);
            }
        __builtin_amdgcn_s_setprio(0);
        __builtin_amdgcn_s_barrier();

#pragma unroll
        for (int m = 0; m < 4; ++m) { af[m][0] = rdA(0, 4 + m, 0); af[m][1] = rdA(0, 4 + m, 1); }
        if (pf) stage(0, 3, e + 2);
        __builtin_amdgcn_s_barrier();
        asm volatile("s_waitcnt lgkmcnt(0)" ::: "memory");
        __builtin_amdgcn_sched_barrier(0);
        __builtin_amdgcn_s_setprio(1);
#pragma unroll
        for (int m = 0; m < 4; ++m)
#pragma unroll
            for (int n = 0; n < 2; ++n) {
                acc[4 + m][n] = mf(af[m][0], bfr[n][0], acc[4 + m][n]);
                acc[4 + m][n] = mf(af[m][1], bfr[n][1], acc[4 + m][n]);
            }
        __builtin_amdgcn_s_setprio(0);
        __builtin_amdgcn_s_barrier();

        if (pf) stage(0, 0, e + 2);
        __builtin_amdgcn_s_barrier();
        __builtin_amdgcn_s_setprio(1);
#pragma unroll
        for (int m = 0; m < 4; ++m)
#pragma unroll
            for (int n = 2; n < 4; ++n) {
                acc[4 + m][n] = mf(af[m][0], bfr[n][0], acc[4 + m][n]);
                acc[4 + m][n] = mf(af[m][1], bfr[n][1], acc[4 + m][n]);
            }
        __builtin_amdgcn_s_setprio(0);
        if (pf) asm volatile("s_waitcnt vmcnt(6)" ::: "memory");
        else    asm volatile("s_waitcnt vmcnt(0)" ::: "memory");
        __builtin_amdgcn_s_barrier();

#pragma unroll
        for (int m = 0; m < 4; ++m) { af[m][0] = rdA(1, m, 0); af[m][1] = rdA(1, m, 1); }
#pragma unroll
        for (int n = 0; n < 4; ++n) { bfr[n][0] = rdB(1, n, 0); bfr[n][1] = rdB(1, n, 1); }
        if (pf) stage(0, 1, e + 2);
        __builtin_amdgcn_s_barrier();
        asm volatile("s_waitcnt lgkmcnt(0)" ::: "memory");
        __builtin_amdgcn_sched_barrier(0);
        __builtin_amdgcn_s_setprio(1);
#pragma unroll
        for (int m = 0; m < 4; ++m)
#pragma unroll
            for (int n = 0; n < 2; ++n) {
                acc[m][n] = mf(af[m][0], bfr[n][0], acc[m][n]);
                acc[m][n] = mf(af[m][1], bfr[n][1], acc[m][n]);
            }
        __builtin_amdgcn_s_setprio(0);
        __builtin_amdgcn_s_barrier();

        if (pf) stage(1, 2, o + 2);
        __builtin_amdgcn_s_barrier();
        __builtin_amdgcn_s_setprio(1);
#pragma unroll
        for (int m = 0; m < 4; ++m)
#pragma unroll
            for (int n = 2; n < 4; ++n) {
                acc[m][n] = mf(af[m][0], bfr[n][0], acc[m][n]);
                acc[m][n] = mf(af[m][1], bfr[n][1], acc[m][n]);
            }
        __builtin_amdgcn_s_setprio(0);
        __builtin_amdgcn_s_barrier();

#pragma unroll
        for (int m = 0; m < 4; ++m) { af[m][0] = rdA(1, 4 + m, 0); af[m][1] = rdA(1, 4 + m, 1); }
        if (pf) stage(1, 3, o + 2);
        __builtin_amdgcn_s_barrier();
        asm volatile("s_waitcnt lgkmcnt(0)" ::: "memory");
        __builtin_amdgcn_sched_barrier(0);
        __builtin_amdgcn_s_setprio(1);
#pragma unroll
        for (int m = 0; m < 4; ++m)
#pragma unroll
            for (int n = 0; n < 2; ++n) {
                acc[4 + m][n] = mf(af[m][0], bfr[n][0], acc[4 + m][n]);
                acc[4 + m][n] = mf(af[m][1], bfr[n][1], acc[4 + m][n]);
            }
        __builtin_amdgcn_s_setprio(0);
        __builtin_amdgcn_s_barrier();

        if (pf) stage(1, 0, o + 2);
        __builtin_amdgcn_s_barrier();
        __builtin_amdgcn_s_setprio(1);
#pragma unroll
        for (int m = 0; m < 4; ++m)
#pragma unroll
            for (int n = 2; n < 4; ++n) {
                acc[4 + m][n] = mf(af[m][0], bfr[n][0], acc[4 + m][n]);
                acc[4 + m][n] = mf(af[m][1], bfr[n][1], acc[4 + m][n]);
            }
        __builtin_amdgcn_s_setprio(0);
        if (pf) asm volatile("s_waitcnt vmcnt(6)" ::: "memory");
        __builtin_amdgcn_s_barrier();
    }

    float* P = nullptr;
    if (EPI == 4) {
        const int z = blockIdx.z;
        P = (z == 0) ? p0 : (z == 1) ? p1 : (z == 2) ? p2 : p3;
    }
#pragma unroll
    for (int m = 0; m < 8; ++m) {
#pragma unroll
        for (int n = 0; n < 4; ++n) {
            int row = bm + wr * 128 + m * 16 + g4 * 4;
            int col = bn + wc * 64 + n * 16 + l15;
#pragma unroll
            for (int r = 0; r < 4; ++r) {
                size_t idx = (size_t)(row + r) * N + col;
                float v = acc[m][n][r];
                if (EPI == 0) {
                    ((float*)C)[idx] = v;
                } else if (EPI == 1) {
                    ((unsigned short*)C)[idx] = f2bf(v);
                } else if (EPI == 2) {
                    ((float*)C)[idx] = v + Res[idx];
                } else if (EPI == 3) {
                    float g = bf2f(G[idx]);
                    ((unsigned short*)C)[idx] = f2bf(g / (1.0f + __expf(-g)) * v);
                } else {
                    P[idx] = v;
                }
            }
        }
    }
}

// Fused per-head RMSNorm (D=128) + RoPE for q and k.
__global__ __launch_bounds__(256)
void qknorm_rope(const float* __restrict__ qkv, const int* __restrict__ positions,
                 const float* __restrict__ qnw, const float* __restrict__ knw,
                 unsigned short* __restrict__ Qo, unsigned short* __restrict__ Ko) {
    const int t    = blockIdx.x;
    const int j    = blockIdx.y * 4 + (threadIdx.x >> 6);  // 0..23
    const int lane = threadIdx.x & 63;
    const float* src = qkv + (size_t)t * 4096 + j * 128;
    float x1 = src[lane];
    float x2 = src[lane + 64];
    float ss = x1 * x1 + x2 * x2;
#pragma unroll
    for (int m = 1; m < 64; m <<= 1) ss += __shfl_xor(ss, m);
    float rs = rsqrtf(ss * (1.0f / 128.0f) + 1e-6f);
    const float* w = (j < 16) ? qnw : knw;
    float n1 = x1 * rs * w[lane];
    float n2 = x2 * rs * w[lane + 64];
    float inv = powf(1.0e6f, -(float)lane * (1.0f / 64.0f));
    float fr = (float)positions[t] * inv;
    float sn, cs;
    sincosf(fr, &sn, &cs);
    float o1 = n1 * cs - n2 * sn;
    float o2 = n2 * cs + n1 * sn;
    if (j < 16) {
        unsigned short* d = Qo + (size_t)t * (kH * kD) + j * kD;
        d[lane] = f2bf(o1);
        d[lane + 64] = f2bf(o2);
    } else {
        unsigned short* d = Ko + (size_t)t * (kHK * kD) + (j - 16) * kD;
        d[lane] = f2bf(o1);
        d[lane + 64] = f2bf(o2);
    }
}

// V transpose: qkv fp32 v-part -> Vt bf16 (1024 x T)
__global__ __launch_bounds__(256)
void vtrans(const float* __restrict__ qkv, unsigned short* __restrict__ Vt) {
    __shared__ float tile[32][33];
    const int t0 = blockIdx.x * 32;
    const int d0 = blockIdx.y * 32;
    const int tc = threadIdx.x & 31;
    const int tr = threadIdx.x >> 5;  // 0..7
#pragma unroll
    for (int i = 0; i < 4; ++i) {
        int trow = tr + i * 8;
        tile[trow][tc] = qkv[(size_t)(t0 + trow) * 4096 + 3072 + d0 + tc];
    }
    __syncthreads();
#pragma unroll
    for (int i = 0; i < 4; ++i) {
        int drow = tr + i * 8;
        Vt[(size_t)(d0 + drow) * kT + t0 + tc] = f2bf(tile[tc][drow]);
    }
}

// Causal flash attention v3: swapped QK^T, in-register softmax + P exchange.
// 4 waves/block share one kv-head; wave owns 16 q rows; KVBLK=64.
// Lane layout after S^T = mfma(K, Q): s[h][r] = S[q=l15][kv=16h+4*g4+r].
__global__ __launch_bounds__(256)
void attn_fwd3(const unsigned short* __restrict__ Q,   // T x (H*D)
               const unsigned short* __restrict__ Kc,  // T x (HK*D)
               const unsigned short* __restrict__ Vt,  // (HK*D) x T
               unsigned short* __restrict__ O) {       // T x (H*D)
    __shared__ unsigned short Ks[2][64 * 128];
    __shared__ unsigned short Vs[2][128 * 64];

    const int tid  = threadIdx.x;
    const int lane = tid & 63;
    const int l15  = lane & 15;
    const int g4   = lane >> 4;
    const int wid  = tid >> 6;
    const int hkk  = blockIdx.y;
    const int h    = hkk * 2 + (wid >> 1);
    // work-balance remap: co-resident pair (2c,2c+1) -> (c, nbx-1-c)
    const int nbx  = gridDim.x;
    const int bx   = blockIdx.x;
    const int bxl  = (bx & 1) ? (nbx - 1 - (bx >> 1)) : (bx >> 1);
    const int q0   = bxl * 32 + (wid & 1) * 16;
    const int nch  = bxl / 2 + 1;
    const int qi   = q0 + l15;   // this lane's q column

    // loop-invariant bpermute addresses
    const int addrA = ((g4 & 1) * 32 + l15) * 4;  // src group 2*(g4&1)
    const int addrB = addrA + 64;                 // src group 2*(g4&1)+1
    const int addrQ = g4 * 80;                    // lane 20*g4 (+4*r)
    const bool hb   = (g4 >> 1) != 0;

    bf16x8 qf[4];
#pragma unroll
    for (int ks = 0; ks < 4; ++ks)
        qf[ks] = *(const bf16x8*)(Q + (size_t)(q0 + l15) * (kH * kD) + h * kD + ks * 32 + g4 * 8);

    f32x4 oacc[8] = {};
    float mrun = -3e38f, lrun = 0.f;
    const float scale = 0.08838834764831845f;  // 1/sqrt(128)

    auto stage = [&](int b, int kv0) {
#pragma unroll
        for (int i = 0; i < 4; ++i) {
            int ch  = tid + i * 256;
            int row = ch >> 4;
            int c16 = ch & 15;
            gload_lds16(Kc + (size_t)(kv0 + row) * (kHK * kD) + hkk * kD
                            + ((c16 ^ (row & 7)) * 8),
                        (char*)Ks[b] + ch * 16);
        }
#pragma unroll
        for (int i = 0; i < 4; ++i) {
            int ch  = tid + i * 256;
            int row = ch >> 3;
            int c8  = ch & 7;
            gload_lds16(Vt + (size_t)(hkk * kD + row) * kT + kv0
                            + ((c8 ^ (row & 7)) * 8),
                        (char*)Vs[b] + ch * 16);
        }
    };

    stage(0, 0);
    __syncthreads();

    for (int c = 0; c < nch; ++c) {
        const int kv0 = c * 64;
        const int b   = c & 1;
        if (c + 1 < nch) stage(b ^ 1, kv0 + 64);

        // ---- S^T = K * Q^T : s[h][r] = S[q=l15][kv=16h+4g4+r] ----
        f32x4 s[4] = {};
        __builtin_amdgcn_s_setprio(1);
#pragma unroll
        for (int hh = 0; hh < 4; ++hh) {
            const int row = hh * 16 + l15;
#pragma unroll
            for (int ks = 0; ks < 4; ++ks) {
                bf16x8 kf = *(const bf16x8*)((const char*)Ks[b]
                              + row * 256 + (((ks * 4 + g4) ^ (row & 7)) * 16));
                s[hh] = mf(kf, qf[ks], s[hh]);
            }
        }
        __builtin_amdgcn_s_setprio(0);

        // ---- scale + causal mask (only near diagonal) ----
        float sv[4][4];
#pragma unroll
        for (int hh = 0; hh < 4; ++hh)
#pragma unroll
            for (int r = 0; r < 4; ++r)
                sv[hh][r] = s[hh][r] * scale;
        if (kv0 + 63 > q0) {
#pragma unroll
            for (int hh = 0; hh < 4; ++hh)
#pragma unroll
                for (int r = 0; r < 4; ++r) {
                    int ki = kv0 + hh * 16 + g4 * 4 + r;
                    if (ki > qi) sv[hh][r] = -3e38f;
                }
        }

        // ---- row max: local tree + 2 shuffles ----
        float m16;
        {
            float a = fmaxf(fmaxf(sv[0][0], sv[0][1]), fmaxf(sv[0][2], sv[0][3]));
            float b2 = fmaxf(fmaxf(sv[1][0], sv[1][1]), fmaxf(sv[1][2], sv[1][3]));
            float c2 = fmaxf(fmaxf(sv[2][0], sv[2][1]), fmaxf(sv[2][2], sv[2][3]));
            float d2 = fmaxf(fmaxf(sv[3][0], sv[3][1]), fmaxf(sv[3][2], sv[3][3]));
            m16 = fmaxf(fmaxf(a, b2), fmaxf(c2, d2));
        }
        m16 = fmaxf(m16, __shfl_xor(m16, 16));
        m16 = fmaxf(m16, __shfl_xor(m16, 32));

        // ---- deferred rescale: only when row max grows ----
        if (__any(m16 > mrun)) {
            float mnew = fmaxf(mrun, m16);
            float corr = __expf(mrun - mnew);
            mrun = mnew;
            lrun *= corr;
            float cr[4];
#pragma unroll
            for (int r = 0; r < 4; ++r)
                cr[r] = __int_as_float(__builtin_amdgcn_ds_bpermute(
                            addrQ + 4 * r, __float_as_int(corr)));
#pragma unroll
            for (int c2 = 0; c2 < 8; ++c2)
#pragma unroll
                for (int r = 0; r < 4; ++r)
                    oacc[c2][r] *= cr[r];
        }

        // ---- P = exp(S - m), row sum ----
        float p[4][4];
        float ps = 0.f;
#pragma unroll
        for (int hh = 0; hh < 4; ++hh)
#pragma unroll
            for (int r = 0; r < 4; ++r) {
                float pe = __expf(sv[hh][r] - mrun);
                p[hh][r] = pe;
                ps += pe;
            }
        ps += __shfl_xor(ps, 16);
        ps += __shfl_xor(ps, 32);
        lrun += ps;

        // ---- pack to bf16 pairs, redistribute to PV A-fragment layout ----
        unsigned pk[4][2];
#pragma unroll
        for (int hh = 0; hh < 4; ++hh) {
            asm("v_cvt_pk_bf16_f32 %0, %1, %2"
                : "=v"(pk[hh][0]) : "v"(p[hh][0]), "v"(p[hh][1]));
            asm("v_cvt_pk_bf16_f32 %0, %1, %2"
                : "=v"(pk[hh][1]) : "v"(p[hh][2]), "v"(p[hh][3]));
        }
        int ex[4][2][2];
#pragma unroll
        for (int hh = 0; hh < 4; ++hh)
#pragma unroll
            for (int ii = 0; ii < 2; ++ii) {
                ex[hh][ii][0] = __builtin_amdgcn_ds_bpermute(addrA, (int)pk[hh][ii]);
                ex[hh][ii][1] = __builtin_amdgcn_ds_bpermute(addrB, (int)pk[hh][ii]);
            }
        union { int w[4]; bf16x8 v; } pu0, pu1;
#pragma unroll
        for (int jw = 0; jw < 4; ++jw) {
            pu0.w[jw] = hb ? ex[1][jw & 1][jw >> 1] : ex[0][jw & 1][jw >> 1];
            pu1.w[jw] = hb ? ex[3][jw & 1][jw >> 1] : ex[2][jw & 1][jw >> 1];
        }
        bf16x8 pa0 = pu0.v;
        bf16x8 pa1 = pu1.v;

        // ---- PV ----
        __builtin_amdgcn_s_setprio(1);
#pragma unroll
        for (int c2 = 0; c2 < 8; ++c2) {
            const int d = c2 * 16 + l15;
            bf16x8 vf0 = *(const bf16x8*)((const char*)Vs[b]
                          + d * 128 + ((g4 ^ (d & 7)) * 16));
            oacc[c2] = mf(pa0, vf0, oacc[c2]);
            bf16x8 vf1 = *(const bf16x8*)((const char*)Vs[b]
                          + d * 128 + ((((4 + g4) ^ (d & 7))) * 16));
            oacc[c2] = mf(pa1, vf1, oacc[c2]);
        }
        __builtin_amdgcn_s_setprio(0);

        __syncthreads();
    }

    // ---- epilogue: divide by row sums (per output row q = q0 + 4g4 + r) ----
    float lr[4];
#pragma unroll
    for (int r = 0; r < 4; ++r)
        lr[r] = __int_as_float(__builtin_amdgcn_ds_bpermute(
                    addrQ + 4 * r, __float_as_int(lrun)));
#pragma unroll
    for (int c2 = 0; c2 < 8; ++c2)
#pragma unroll
        for (int r = 0; r < 4; ++r) {
            float v = oacc[c2][r] / lr[r];
            O[(size_t)(q0 + g4 * 4 + r) * (kH * kD) + h * kD + c2 * 16 + l15] = f2bf(v);
        }
}

}  // namespace

extern "C" void kernel_launch(void* const* d_in, const int* in_sizes, int n_in,
                              void* d_out, int out_size, void* d_ws, size_t ws_size,
                              hipStream_t stream) {
    (void)in_sizes; (void)n_in; (void)out_size; (void)ws_size;

    const int*   positions = (const int*)  d_in[0];
    const float* hidden    = (const float*)d_in[1];
    const float* wq  = (const float*)d_in[2];
    const float* wk  = (const float*)d_in[3];
    const float* wv  = (const float*)d_in[4];
    const float* wo  = (const float*)d_in[5];
    const float* qnw = (const float*)d_in[6];
    const float* knw = (const float*)d_in[7];
    const float* ln1 = (const float*)d_in[8];
    const float* ln2 = (const float*)d_in[9];
    const float* wg  = (const float*)d_in[10];
    const float* wu  = (const float*)d_in[11];
    const float* wd  = (const float*)d_in[12];

    char* ws = (char*)d_ws;
    unsigned short* WQKV = (unsigned short*)(ws + 0);          // 4096x2048 bf16
    unsigned short* WO   = (unsigned short*)(ws + 16777216);   // 2048x2048
    unsigned short* WG   = (unsigned short*)(ws + 25165824);   // 6144x2048
    unsigned short* WU   = (unsigned short*)(ws + 50331648);   // 6144x2048
    unsigned short* WD   = (unsigned short*)(ws + 75497472);   // 2048x6144
    unsigned short* XN1  = (unsigned short*)(ws + 100663296);  // T x 2048
    unsigned short* OATT = (unsigned short*)(ws + 109051904);  // T x 2048
    float*          H1   = (float*)(ws + 117440512);           // T x 2048 fp32
    unsigned short* XN2  = (unsigned short*)(ws + 134217728);  // T x 2048
    float*          QKVF = (float*)(ws + 142606336);           // T x 4096 fp32
    unsigned short* QB   = (unsigned short*)(ws + 176160768);  // T x 2048
    unsigned short* KB   = (unsigned short*)(ws + 184549376);  // T x 1024
    unsigned short* VT   = (unsigned short*)(ws + 188743680);  // 1024 x T
    unsigned short* GATE = (unsigned short*)(ws + 142606336);  // T x 6144 (alias QKVF)
    unsigned short* ACT  = (unsigned short*)(ws + 167772160);  // T x 6144 (alias)

    float* OP0 = (float*)(ws + 142606336);
    float* OP1 = (float*)(ws + 159383552);
    float* OP2 = (float*)(ws + 176160768);
    float* OP3 = (float*)(ws + 0);
    float* DP0 = (float*)(ws + 0);
    float* DP1 = (float*)(ws + 16777216);
    float* DP2 = (float*)(ws + 33554432);
    float* DP3 = (float*)(ws + 142606336);

    auto cvt = [&](const float* s, unsigned short* dst, size_t n) {
        int n4 = (int)(n / 4);
        cvt_f32_bf16<<<dim3((n4 + 255) / 256), dim3(256), 0, stream>>>(s, dst, n4);
    };

    cvt(wq, WQKV,                 (size_t)kH  * kD * kHid);
    cvt(wk, WQKV + 2048 * kHid,   (size_t)kHK * kD * kHid);
    cvt(wv, WQKV + 3072 * kHid,   (size_t)kHK * kD * kHid);
    cvt(wo, WO,                   (size_t)kHid * kH * kD);
    cvt(wg, WG,                   (size_t)kFF * kHid);
    cvt(wu, WU,                   (size_t)kFF * kHid);
    cvt(wd, WD,                   (size_t)kHid * kFF);

    rmsnorm_k<<<dim3(kT), dim3(256), 0, stream>>>(hidden, ln1, XN1);

    gemm256<0><<<dim3(4096 / 256, kT / 256), dim3(512), 0, stream>>>(
        XN1, WQKV, QKVF, nullptr, nullptr, kT, 4096, kHid, kHid,
        nullptr, nullptr, nullptr, nullptr);

    qknorm_rope<<<dim3(kT, 6), dim3(256), 0, stream>>>(QKVF, positions, qnw, knw, QB, KB);

    vtrans<<<dim3(kT / 32, 1024 / 32), dim3(256), 0, stream>>>(QKVF, VT);

    attn_fwd3<<<dim3(kT / 32, kHK), dim3(256), 0, stream>>>(QB, KB, VT, OATT);

    gemm256<4><<<dim3(kHid / 256, kT / 256, 4), dim3(512), 0, stream>>>(
        OATT, WO, nullptr, nullptr, nullptr, kT, kHid, kHid, 512,
        OP0, OP1, OP2, OP3);
    reduce4<<<dim3(kT * kHid / 4 / 256), dim3(256), 0, stream>>>(
        OP0, OP1, OP2, OP3, hidden, H1, kT * kHid / 4);

    rmsnorm_k<<<dim3(kT), dim3(256), 0, stream>>>(H1, ln2, XN2);

    gemm256<1><<<dim3(kFF / 256, kT / 256), dim3(512), 0, stream>>>(
        XN2, WG, GATE, nullptr, nullptr, kT, kFF, kHid, kHid,
        nullptr, nullptr, nullptr, nullptr);

    gemm256<3><<<dim3(kFF / 256, kT / 256), dim3(512), 0, stream>>>(
        XN2, WU, ACT, nullptr, GATE, kT, kFF, kHid, kHid,
        nullptr, nullptr, nullptr, nullptr);

    gemm256<4><<<dim3(kHid / 256, kT / 256, 4), dim3(512), 0, stream>>>(
        ACT, WD, nullptr, nullptr, nullptr, kT, kHid, kFF, 1536,
        DP0, DP1, DP2, DP3);
    reduce4<<<dim3(kT * kHid / 4 / 256), dim3(256), 0, stream>>>(
        DP0, DP1, DP2, DP3, H1, (float*)d_out, kT * kHid / 4);
}